// Round 1
// 532.326 us; speedup vs baseline: 1.0820x; 1.0820x over previous
//
#include <hip/hip_runtime.h>
#include <math.h>
#include <stdint.h>

// LinearAttention  N=4, S=8192, D_IN=1024, ATTN_DIM=1024, OUT_DIM=1024
// R5: 8-phase counted-vmcnt rewrite (T3+T4+T5 on top of existing T2 swizzle).
//  - qkv: BM=256, BN=64x3, BK=64, 8 waves (4m x 2n), 4 phases/K-tile,
//    12 MFMA/phase, LDS 120KB double-buffered, vmcnt(2) at P4/P8 only.
//  - out: 256x256 template, 8 waves (2m x 4n), snake quadrants, 16 MFMA/phase,
//    LDS 128KB.
//  - raw s_barrier (asm, memory clobber) so the compiler never drains vmcnt(0);
//    lgkmcnt(0)+sched_barrier(0) before each MFMA cluster; setprio around MFMA.
//  - wtrans 4 launches -> 1.
// ws layout unchanged: Q 64M | xb half 32M | wT 8M | KV/Ks.

#define S_LEN 8192

typedef __attribute__((ext_vector_type(8))) __bf16 bf16x8;
typedef __attribute__((ext_vector_type(8))) unsigned short ushort8;
typedef __attribute__((ext_vector_type(4))) float f32x4;

__device__ __forceinline__ unsigned short f2bf(float f) {
    unsigned int u = __builtin_bit_cast(unsigned int, f);
    unsigned int r = (u + 0x7fffu + ((u >> 16) & 1u)) >> 16;   // RNE
    return (unsigned short)r;
}
__device__ __forceinline__ float bf2f(unsigned short s) {
    unsigned int u = ((unsigned int)s) << 16;
    return __builtin_bit_cast(float, u);
}
__device__ __forceinline__ float elu1(float v) { return v > 0.f ? v + 1.f : __expf(v); }
__device__ __forceinline__ float gelu_tanh(float v) {
    float u = 1.5957691216057308f * (v + 0.044715f * v * v * v);
    float e = __expf(u);
    float th = 1.f - 2.f / (e + 1.f);
    return 0.5f * v * (1.f + th);
}
__device__ __forceinline__ void glds16(const void* g, void* l) {
    __builtin_amdgcn_global_load_lds(
        (const __attribute__((address_space(1))) unsigned int*)(uintptr_t)g,
        (__attribute__((address_space(3))) unsigned int*)(uintptr_t)l, 16, 0, 0);
}

#define KBAR()  asm volatile("s_barrier" ::: "memory")
#define LGKM0() do { asm volatile("s_waitcnt lgkmcnt(0)" ::: "memory"); \
                     __builtin_amdgcn_sched_barrier(0); } while (0)
#define VM2()   asm volatile("s_waitcnt vmcnt(2)" ::: "memory")
#define VM0()   asm volatile("s_waitcnt vmcnt(0)" ::: "memory")

// ---------------------------------------------------------------------------
// x fp32 -> bf16, one half (16384 rows) per call
// ---------------------------------------------------------------------------
__global__ __launch_bounds__(256) void xconv(const float* __restrict__ x,
                                             unsigned short* __restrict__ xb)
{
    const size_t base = ((size_t)blockIdx.x * 256 + threadIdx.x) * 8;
    float4 a = *(const float4*)&x[base];
    float4 b = *(const float4*)&x[base + 4];
    ushort8 o;
    o[0] = f2bf(a.x); o[1] = f2bf(a.y); o[2] = f2bf(a.z); o[3] = f2bf(a.w);
    o[4] = f2bf(b.x); o[5] = f2bf(b.y); o[6] = f2bf(b.z); o[7] = f2bf(b.w);
    *(ushort8*)&xb[base] = o;
}

// ---------------------------------------------------------------------------
// weight transpose + convert, all 4 matrices in one launch (blockIdx.z)
// ---------------------------------------------------------------------------
__global__ __launch_bounds__(256) void wtrans(const float* __restrict__ wq,
                                              const float* __restrict__ wk,
                                              const float* __restrict__ wv,
                                              const float* __restrict__ wo,
                                              unsigned short* __restrict__ wT)
{
    __shared__ float tile[64][65];
    const int z = blockIdx.z;
    const float* w = (z == 0) ? wq : (z == 1) ? wk : (z == 2) ? wv : wo;
    unsigned short* dst = wT + (size_t)z * 1048576;
    const int t  = threadIdx.x;
    const int n0 = blockIdx.x * 64;
    const int k0 = blockIdx.y * 64;
    const int r  = t >> 2;
    const int c4 = (t & 3) * 16;
    #pragma unroll
    for (int j = 0; j < 4; ++j) {
        float4 v = *(const float4*)&w[(size_t)(k0 + r) * 1024 + n0 + c4 + j * 4];
        tile[r][c4 + j * 4 + 0] = v.x; tile[r][c4 + j * 4 + 1] = v.y;
        tile[r][c4 + j * 4 + 2] = v.z; tile[r][c4 + j * 4 + 3] = v.w;
    }
    __syncthreads();
    const int nn = t >> 2;
    const int kc = (t & 3) * 16;
    ushort8 o0, o1;
    #pragma unroll
    for (int j = 0; j < 8; ++j) o0[j] = f2bf(tile[kc + j][nn]);
    #pragma unroll
    for (int j = 0; j < 8; ++j) o1[j] = f2bf(tile[kc + 8 + j][nn]);
    *(ushort8*)&dst[(size_t)(n0 + nn) * 1024 + k0 + kc]     = o0;
    *(ushort8*)&dst[(size_t)(n0 + nn) * 1024 + k0 + kc + 8] = o1;
}

// ---------------------------------------------------------------------------
// Phase A: fused QKV.  BM=256, BN=64 per matrix, BK=64, 8 waves (4m x 2n),
// wave tile 64x32 per matrix.  8-phase pipelined K-loop, vmcnt(2) at P4/P8.
// ---------------------------------------------------------------------------
__global__ __launch_bounds__(512) void qkv_mfma(
    const unsigned short* __restrict__ xb,       // half: [16384,1024] bf16
    const unsigned short* __restrict__ wqT,
    const unsigned short* __restrict__ wkT,
    const unsigned short* __restrict__ wvT,
    const float* __restrict__ bq, const float* __restrict__ bk,
    const float* __restrict__ bv,
    unsigned short* __restrict__ Qout,           // full [32768,1024]
    float* __restrict__ KV, float* __restrict__ Ks,
    int moff)
{
    __shared__ unsigned short Alds[2][256 * 64];     // 64 KB
    __shared__ unsigned short Blds[3][2][64 * 64];   // 48 KB
    __shared__ float redkv[16][64];
    __shared__ float redks[16][64];

    const int t    = threadIdx.x;
    const int h0   = blockIdx.x * 64;
    const int m0   = blockIdx.y * 256;
    const int mg   = moff + m0;
    const int bidx = mg >> 13;

    const int lane = t & 63, wid = t >> 6;
    const int wm = wid >> 1, wn = wid & 1;
    const int lr = lane & 15, quad = lane >> 4;

    const int sA   = wid * 64 + lane;
    const int xks0 = ((quad)     ^ (lr & 7)) * 8;
    const int xks1 = ((quad | 4) ^ (lr & 7)) * 8;
    const int arow = (wm * 64 + lr) * 64;
    const int brow = (wn * 32 + lr) * 64;

    // A unit u = 64 rows (512 chunks); per wave: 8 rows, 1 glds each.
    auto stA = [&](int kt, int u, int buf) {
        const int s = u * 512 + sA;
        const int r = s >> 3;
        const int j = (s & 7) ^ (r & 7);
        glds16(&xb[(size_t)(m0 + r) * 1024 + kt * 64 + j * 8],
               &Alds[buf][(u * 512 + wid * 64) * 8]);
    };
    // B matrix tile = 64 rows = 1 unit.
    auto stB = [&](const unsigned short* w, int mat, int kt, int buf) {
        const int r = sA >> 3;
        const int j = (sA & 7) ^ (r & 7);
        glds16(&w[(size_t)(h0 + r) * 1024 + kt * 64 + j * 8],
               &Blds[mat][buf][(wid * 64) * 8]);
    };

    f32x4 accq[4][2], acck[4][2], accv[4][2];
    #pragma unroll
    for (int mi = 0; mi < 4; ++mi)
        #pragma unroll
        for (int nj = 0; nj < 2; ++nj) {
            accq[mi][nj] = (f32x4){0.f, 0.f, 0.f, 0.f};
            acck[mi][nj] = (f32x4){0.f, 0.f, 0.f, 0.f};
            accv[mi][nj] = (f32x4){0.f, 0.f, 0.f, 0.f};
        }

    // prologue: tile0 full (A 4 units + B 3), then A1 u0,u1 left in flight
    #pragma unroll
    for (int u = 0; u < 4; ++u) stA(0, u, 0);
    stB(wqT, 0, 0, 0); stB(wkT, 1, 0, 0); stB(wvT, 2, 0, 0);
    stA(1, 0, 1); stA(1, 1, 1);
    VM2();
    KBAR();

    bf16x8 af[4];

#define QKV_LDA(BUF, XK)                                                        \
    {                                                                           \
        _Pragma("unroll")                                                       \
        for (int mi = 0; mi < 4; ++mi)                                          \
            af[mi] = __builtin_bit_cast(bf16x8,                                 \
                *(const ushort8*)&Alds[BUF][arow + mi * 1024 + (XK)]);          \
    }

#define QKV_PHASE(BUF, NJ, XK, STG, WT)                                         \
    {                                                                           \
        bf16x8 b0 = __builtin_bit_cast(bf16x8,                                  \
            *(const ushort8*)&Blds[0][BUF][brow + (NJ) * 1024 + (XK)]);         \
        bf16x8 b1 = __builtin_bit_cast(bf16x8,                                  \
            *(const ushort8*)&Blds[1][BUF][brow + (NJ) * 1024 + (XK)]);         \
        bf16x8 b2 = __builtin_bit_cast(bf16x8,                                  \
            *(const ushort8*)&Blds[2][BUF][brow + (NJ) * 1024 + (XK)]);         \
        STG;                                                                    \
        KBAR();                                                                 \
        LGKM0();                                                                \
        __builtin_amdgcn_s_setprio(1);                                          \
        _Pragma("unroll")                                                       \
        for (int mi = 0; mi < 4; ++mi) {                                        \
            accq[mi][NJ] = __builtin_amdgcn_mfma_f32_16x16x32_bf16(af[mi], b0, accq[mi][NJ], 0, 0, 0); \
            acck[mi][NJ] = __builtin_amdgcn_mfma_f32_16x16x32_bf16(af[mi], b1, acck[mi][NJ], 0, 0, 0); \
            accv[mi][NJ] = __builtin_amdgcn_mfma_f32_16x16x32_bf16(af[mi], b2, accv[mi][NJ], 0, 0, 0); \
        }                                                                       \
        __builtin_amdgcn_s_setprio(0);                                          \
        WT;                                                                     \
        KBAR();                                                                 \
    }

    for (int i = 0; i < 8; ++i) {
        const int t1 = 2 * i + 1;
        // ---- tile 2i (buf 0) ----
        QKV_LDA(0, xks0);                                                     // P1
        QKV_PHASE(0, 0, xks0, { stA(t1, 2, 1); stA(t1, 3, 1); }, {});
        QKV_PHASE(0, 1, xks0, { stB(wqT, 0, t1, 1); stB(wkT, 1, t1, 1); }, {}); // P2
        QKV_LDA(0, xks1);                                                     // P3
        QKV_PHASE(0, 0, xks1, { stB(wvT, 2, t1, 1); }, {});
        if (i < 7) {                                                          // P4
            QKV_PHASE(0, 1, xks1, { stA(t1 + 1, 0, 0); stA(t1 + 1, 1, 0); }, VM2());
        } else {
            QKV_PHASE(0, 1, xks1, {}, VM0());
        }
        // ---- tile 2i+1 (buf 1) ----
        QKV_LDA(1, xks0);                                                     // P5
        if (i < 7) {
            QKV_PHASE(1, 0, xks0, { stA(t1 + 1, 2, 0); stA(t1 + 1, 3, 0); }, {});
            QKV_PHASE(1, 1, xks0, { stB(wqT, 0, t1 + 1, 0); stB(wkT, 1, t1 + 1, 0); }, {}); // P6
            QKV_LDA(1, xks1);                                                 // P7
            QKV_PHASE(1, 0, xks1, { stB(wvT, 2, t1 + 1, 0); }, {});
            QKV_PHASE(1, 1, xks1, { stA(t1 + 2, 0, 1); stA(t1 + 2, 1, 1); }, VM2()); // P8
        } else {
            QKV_PHASE(1, 0, xks0, {}, {});
            QKV_PHASE(1, 1, xks0, {}, {});
            QKV_LDA(1, xks1);
            QKV_PHASE(1, 0, xks1, {}, {});
            QKV_PHASE(1, 1, xks1, {}, {});
        }
    }
#undef QKV_LDA
#undef QKV_PHASE

    // ---- epilogue: bias, elu+1, Q store (bf16), KV/Ksum partials ----
    float bqv[2], bkv[2], bvv[2];
    #pragma unroll
    for (int nj = 0; nj < 2; ++nj) {
        const int h = h0 + wn * 32 + nj * 16 + lr;
        bqv[nj] = bq[h]; bkv[nj] = bk[h]; bvv[nj] = bv[h];
    }
    float kvp[2] = {0.f, 0.f}, ksp[2] = {0.f, 0.f};
    #pragma unroll
    for (int mi = 0; mi < 4; ++mi)
        #pragma unroll
        for (int nj = 0; nj < 2; ++nj) {
            const int h = h0 + wn * 32 + nj * 16 + lr;
            #pragma unroll
            for (int r = 0; r < 4; ++r) {
                const int m = mg + wm * 64 + mi * 16 + quad * 4 + r;
                float q = elu1(accq[mi][nj][r] + bqv[nj]);
                Qout[(size_t)m * 1024 + h] = f2bf(q);
                float kk = elu1(acck[mi][nj][r] + bkv[nj]);
                float vv = accv[mi][nj][r] + bvv[nj];
                kvp[nj] = fmaf(kk, vv, kvp[nj]);
                ksp[nj] += kk;
            }
        }
    #pragma unroll
    for (int nj = 0; nj < 2; ++nj) {
        redkv[wm * 4 + quad][wn * 32 + nj * 16 + lr] = kvp[nj];
        redks[wm * 4 + quad][wn * 32 + nj * 16 + lr] = ksp[nj];
    }
    __syncthreads();
    if (t < 64) {
        float s = 0.f;
        #pragma unroll
        for (int g = 0; g < 16; ++g) s += redkv[g][t];
        atomicAdd(&KV[bidx * 1024 + h0 + t], s);
    } else if (t < 128) {
        const int c = t - 64;
        float s = 0.f;
        #pragma unroll
        for (int g = 0; g < 16; ++g) s += redks[g][c];
        atomicAdd(&Ks[bidx * 1024 + h0 + c], s);
    }
}

// ---------------------------------------------------------------------------
// V' = Q*KV / (Q*Ksum + 1e-6), elementwise in-place on Q (bf16)
// ---------------------------------------------------------------------------
__global__ __launch_bounds__(256) void vprime(
    unsigned short* __restrict__ Q,
    const float* __restrict__ KV, const float* __restrict__ Ks)
{
    const size_t idx  = (size_t)blockIdx.x * 256 + threadIdx.x;
    const size_t base = idx * 8;
    const int h = (int)(base & 1023);
    const int n = (int)(base >> 23);
    ushort8 q8 = *(ushort8*)&Q[base];
    const float* kvp = &KV[n * 1024 + h];
    const float* ksp = &Ks[n * 1024 + h];
    ushort8 o;
    #pragma unroll
    for (int j = 0; j < 8; ++j) {
        float qf = bf2f(q8[j]);
        float vp = qf * kvp[j] * __builtin_amdgcn_rcpf(fmaf(qf, ksp[j], 1e-6f));
        o[j] = f2bf(vp);
    }
    *(ushort8*)&Q[base] = o;
}

// ---------------------------------------------------------------------------
// Phase B: out = gelu(V' @ wo + bo).  256x256 tile, BK=64, 8 waves (2m x 4n),
// snake-quadrant 8-phase schedule, 16 MFMA/phase, LDS 128KB.
// ---------------------------------------------------------------------------
__global__ __launch_bounds__(512) void out_mfma(
    const unsigned short* __restrict__ Vp,
    const unsigned short* __restrict__ woT,
    const float* __restrict__ bo, float* __restrict__ out)
{
    __shared__ unsigned short Alds[2][256 * 64];   // 64 KB
    __shared__ unsigned short Blds[2][256 * 64];   // 64 KB

    const int t  = threadIdx.x;
    const int h0 = blockIdx.x * 256;
    const int m0 = blockIdx.y * 256;

    const int lane = t & 63, wid = t >> 6;
    const int wm = wid >> 2, wn = wid & 3;
    const int lr = lane & 15, quad = lane >> 4;

    const int sA   = wid * 64 + lane;
    const int xks0 = ((quad)     ^ (lr & 7)) * 8;
    const int xks1 = ((quad | 4) ^ (lr & 7)) * 8;
    const int arow = (wm * 128 + lr) * 64;
    const int brow = (wn * 64 + lr) * 64;

    auto stA = [&](int kt, int u, int buf) {
        const int s = u * 512 + sA;
        const int r = s >> 3;
        const int j = (s & 7) ^ (r & 7);
        glds16(&Vp[(size_t)(m0 + r) * 1024 + kt * 64 + j * 8],
               &Alds[buf][(u * 512 + wid * 64) * 8]);
    };
    auto stB = [&](int kt, int u, int buf) {
        const int s = u * 512 + sA;
        const int r = s >> 3;
        const int j = (s & 7) ^ (r & 7);
        glds16(&woT[(size_t)(h0 + r) * 1024 + kt * 64 + j * 8],
               &Blds[buf][(u * 512 + wid * 64) * 8]);
    };

    f32x4 acc[8][4];
    #pragma unroll
    for (int mr = 0; mr < 8; ++mr)
        #pragma unroll
        for (int nc = 0; nc < 4; ++nc) acc[mr][nc] = (f32x4){0.f, 0.f, 0.f, 0.f};

    // prologue
    #pragma unroll
    for (int u = 0; u < 4; ++u) stA(0, u, 0);
    #pragma unroll
    for (int u = 0; u < 4; ++u) stB(0, u, 0);
    stA(1, 0, 1); stA(1, 1, 1);
    VM2();
    KBAR();

    bf16x8 af[4][2], bf_[2][2];

#define OUT_LDA(BUF, MH)                                                        \
    {                                                                           \
        _Pragma("unroll")                                                       \
        for (int mi = 0; mi < 4; ++mi) {                                        \
            af[mi][0] = __builtin_bit_cast(bf16x8,                              \
                *(const ushort8*)&Alds[BUF][arow + (MH) * 4096 + mi * 1024 + xks0]); \
            af[mi][1] = __builtin_bit_cast(bf16x8,                              \
                *(const ushort8*)&Alds[BUF][arow + (MH) * 4096 + mi * 1024 + xks1]); \
        }                                                                       \
    }

#define OUT_LDB(BUF, NH)                                                        \
    {                                                                           \
        _Pragma("unroll")                                                       \
        for (int nj = 0; nj < 2; ++nj) {                                        \
            bf_[nj][0] = __builtin_bit_cast(bf16x8,                             \
                *(const ushort8*)&Blds[BUF][brow + (NH) * 2048 + nj * 1024 + xks0]); \
            bf_[nj][1] = __builtin_bit_cast(bf16x8,                             \
                *(const ushort8*)&Blds[BUF][brow + (NH) * 2048 + nj * 1024 + xks1]); \
        }                                                                       \
    }

#define OUT_PHASE(MH, NH, STG, WT)                                              \
    {                                                                           \
        STG;                                                                    \
        KBAR();                                                                 \
        LGKM0();                                                                \
        __builtin_amdgcn_s_setprio(1);                                          \
        _Pragma("unroll")                                                       \
        for (int mi = 0; mi < 4; ++mi)                                          \
            _Pragma("unroll")                                                   \
            for (int nj = 0; nj < 2; ++nj) {                                    \
                acc[(MH) * 4 + mi][(NH) * 2 + nj] = __builtin_amdgcn_mfma_f32_16x16x32_bf16( \
                    af[mi][0], bf_[nj][0], acc[(MH) * 4 + mi][(NH) * 2 + nj], 0, 0, 0); \
                acc[(MH) * 4 + mi][(NH) * 2 + nj] = __builtin_amdgcn_mfma_f32_16x16x32_bf16( \
                    af[mi][1], bf_[nj][1], acc[(MH) * 4 + mi][(NH) * 2 + nj], 0, 0, 0); \
            }                                                                   \
        __builtin_amdgcn_s_setprio(0);                                          \
        WT;                                                                     \
        KBAR();                                                                 \
    }

    for (int i = 0; i < 8; ++i) {
        const int t1 = 2 * i + 1;
        // ---- tile 2i (buf 0), snake: (0,0) (0,1) (1,1) (1,0) ----
        OUT_LDA(0, 0); OUT_LDB(0, 0);                                          // P1
        OUT_PHASE(0, 0, { stA(t1, 2, 1); stA(t1, 3, 1); }, {});
        OUT_LDB(0, 1);                                                         // P2
        OUT_PHASE(0, 1, { stB(t1, 0, 1); stB(t1, 1, 1); }, {});
        OUT_LDA(0, 1);                                                         // P3
        OUT_PHASE(1, 1, { stB(t1, 2, 1); stB(t1, 3, 1); }, {});
        OUT_LDB(0, 0);                                                         // P4
        if (i < 7) {
            OUT_PHASE(1, 0, { stA(t1 + 1, 0, 0); stA(t1 + 1, 1, 0); }, VM2());
        } else {
            OUT_PHASE(1, 0, {}, VM0());
        }
        // ---- tile 2i+1 (buf 1) ----
        OUT_LDA(1, 0); OUT_LDB(1, 0);                                          // P5
        if (i < 7) {
            OUT_PHASE(0, 0, { stA(t1 + 1, 2, 0); stA(t1 + 1, 3, 0); }, {});
            OUT_LDB(1, 1);                                                     // P6
            OUT_PHASE(0, 1, { stB(t1 + 1, 0, 0); stB(t1 + 1, 1, 0); }, {});
            OUT_LDA(1, 1);                                                     // P7
            OUT_PHASE(1, 1, { stB(t1 + 1, 2, 0); stB(t1 + 1, 3, 0); }, {});
            OUT_LDB(1, 0);                                                     // P8
            OUT_PHASE(1, 0, { stA(t1 + 2, 0, 1); stA(t1 + 2, 1, 1); }, VM2());
        } else {
            OUT_PHASE(0, 0, {}, {});
            OUT_LDB(1, 1);
            OUT_PHASE(0, 1, {}, {});
            OUT_LDA(1, 1);
            OUT_PHASE(1, 1, {}, {});
            OUT_LDB(1, 0);
            OUT_PHASE(1, 0, {}, {});
        }
    }
#undef OUT_LDA
#undef OUT_LDB
#undef OUT_PHASE

    float bov[4];
    #pragma unroll
    for (int nc = 0; nc < 4; ++nc) bov[nc] = bo[h0 + wn * 64 + nc * 16 + lr];
    #pragma unroll
    for (int mr = 0; mr < 8; ++mr)
        #pragma unroll
        for (int nc = 0; nc < 4; ++nc) {
            const int h = h0 + wn * 64 + nc * 16 + lr;
            #pragma unroll
            for (int r = 0; r < 4; ++r) {
                const int m = m0 + wm * 128 + mr * 16 + quad * 4 + r;
                out[(size_t)m * 1024 + h] = gelu_tanh(acc[mr][nc][r] + bov[nc]);
            }
        }
}

extern "C" void kernel_launch(void* const* d_in, const int* in_sizes, int n_in,
                              void* d_out, int out_size, void* d_ws, size_t ws_size,
                              hipStream_t stream)
{
    const float* x  = (const float*)d_in[0];
    const float* wq = (const float*)d_in[1];
    const float* bq = (const float*)d_in[2];
    const float* wk = (const float*)d_in[3];
    const float* bk = (const float*)d_in[4];
    const float* wv = (const float*)d_in[5];
    const float* bv = (const float*)d_in[6];
    const float* wo = (const float*)d_in[7];
    const float* bo = (const float*)d_in[8];
    float* out = (float*)d_out;

    // ws layout (bytes):
    //   [0, 64M)        Q / V' bf16  (32768 x 1024)
    //   [64M, 96M)      xb bf16 half (16384 x 1024), reused for both halves
    //   [96M, 104M)     wqT, wkT, wvT, woT bf16 (2MB each, contiguous)
    //   [104M, ...)     KV fp32 [4,1024], Ks fp32 [4,1024]
    char* wsb = (char*)d_ws;
    unsigned short* Qws = (unsigned short*)wsb;
    unsigned short* xb  = (unsigned short*)(wsb + 67108864ULL);
    unsigned short* wqT = (unsigned short*)(wsb + 100663296ULL);
    unsigned short* wkT = wqT + 1048576;
    unsigned short* wvT = wkT + 1048576;
    unsigned short* woT = wvT + 1048576;
    float* KV = (float*)(wsb + 100663296ULL + 4ULL * 2097152);
    float* Ks = KV + 4 * 1024;

    hipMemsetAsync(KV, 0, 2 * 4 * 1024 * sizeof(float), stream);

    wtrans<<<dim3(16, 16, 4), 256, 0, stream>>>(wq, wk, wv, wo, wqT);

    for (int half = 0; half < 2; ++half) {
        xconv<<<8192, 256, 0, stream>>>(x + (size_t)half * 16384 * 1024, xb);
        qkv_mfma<<<dim3(16, 64), 512, 0, stream>>>(xb, wqT, wkT, wvT, bq, bk, bv,
                                                   Qws, KV, Ks, half * 16384);
    }
    vprime<<<16384, 256, 0, stream>>>(Qws, KV, Ks);
    out_mfma<<<dim3(4, 128), 512, 0, stream>>>(Qws, woT, bo, out);
}

// Round 2
// 526.871 us; speedup vs baseline: 1.0932x; 1.0104x over previous
//
#include <hip/hip_runtime.h>
#include <math.h>
#include <stdint.h>

// LinearAttention  N=4, S=8192, D_IN=1024, ATTN_DIM=1024, OUT_DIM=1024
// R6: qkv phase-merge.  2 phases per K-tile (24 MFMA/phase instead of 12) to
// amortize the ~450-cyc fixed per-phase cost (2 barriers + lgkm drain).
// Counted-vmcnt horizon preserved by TRIPLE-buffering B (3 mats x 3 bufs x 8KB
// = 72KB; A stays double-buffered 64KB; total 144KB LDS, 1 block/CU as before).
// Schedule per K-tile t (phases f=2t, 2t+1):
//   even f: read(t,ks0); stage A(t+1) all 4 units
//   odd  f: read(t,ks1); stage B(t+2) q,k,v; s_waitcnt vmcnt(3)  <- keeps
//           B(t+2) in flight, drains A(t+1)+B(t+1) (strictly older)
// out_mfma unchanged (validated 256^2 8-phase template; its 2-phase variant
// would be LDS-read-bound).  Numerics identical to R5.

#define S_LEN 8192

typedef __attribute__((ext_vector_type(8))) __bf16 bf16x8;
typedef __attribute__((ext_vector_type(8))) unsigned short ushort8;
typedef __attribute__((ext_vector_type(4))) float f32x4;

__device__ __forceinline__ unsigned short f2bf(float f) {
    unsigned int u = __builtin_bit_cast(unsigned int, f);
    unsigned int r = (u + 0x7fffu + ((u >> 16) & 1u)) >> 16;   // RNE
    return (unsigned short)r;
}
__device__ __forceinline__ float bf2f(unsigned short s) {
    unsigned int u = ((unsigned int)s) << 16;
    return __builtin_bit_cast(float, u);
}
__device__ __forceinline__ float elu1(float v) { return v > 0.f ? v + 1.f : __expf(v); }
__device__ __forceinline__ float gelu_tanh(float v) {
    float u = 1.5957691216057308f * (v + 0.044715f * v * v * v);
    float e = __expf(u);
    float th = 1.f - 2.f / (e + 1.f);
    return 0.5f * v * (1.f + th);
}
__device__ __forceinline__ void glds16(const void* g, void* l) {
    __builtin_amdgcn_global_load_lds(
        (const __attribute__((address_space(1))) unsigned int*)(uintptr_t)g,
        (__attribute__((address_space(3))) unsigned int*)(uintptr_t)l, 16, 0, 0);
}

#define KBAR()  asm volatile("s_barrier" ::: "memory")
#define LGKM0() do { asm volatile("s_waitcnt lgkmcnt(0)" ::: "memory"); \
                     __builtin_amdgcn_sched_barrier(0); } while (0)
#define VM3()   asm volatile("s_waitcnt vmcnt(3)" ::: "memory")
#define VM2()   asm volatile("s_waitcnt vmcnt(2)" ::: "memory")
#define VM0()   asm volatile("s_waitcnt vmcnt(0)" ::: "memory")

#define LDF(P, OFF) __builtin_bit_cast(bf16x8, *(const ushort8*)&(P)[OFF])

// ---------------------------------------------------------------------------
// x fp32 -> bf16, one half (16384 rows) per call
// ---------------------------------------------------------------------------
__global__ __launch_bounds__(256) void xconv(const float* __restrict__ x,
                                             unsigned short* __restrict__ xb)
{
    const size_t base = ((size_t)blockIdx.x * 256 + threadIdx.x) * 8;
    float4 a = *(const float4*)&x[base];
    float4 b = *(const float4*)&x[base + 4];
    ushort8 o;
    o[0] = f2bf(a.x); o[1] = f2bf(a.y); o[2] = f2bf(a.z); o[3] = f2bf(a.w);
    o[4] = f2bf(b.x); o[5] = f2bf(b.y); o[6] = f2bf(b.z); o[7] = f2bf(b.w);
    *(ushort8*)&xb[base] = o;
}

// ---------------------------------------------------------------------------
// weight transpose + convert, all 4 matrices in one launch (blockIdx.z)
// ---------------------------------------------------------------------------
__global__ __launch_bounds__(256) void wtrans(const float* __restrict__ wq,
                                              const float* __restrict__ wk,
                                              const float* __restrict__ wv,
                                              const float* __restrict__ wo,
                                              unsigned short* __restrict__ wT)
{
    __shared__ float tile[64][65];
    const int z = blockIdx.z;
    const float* w = (z == 0) ? wq : (z == 1) ? wk : (z == 2) ? wv : wo;
    unsigned short* dst = wT + (size_t)z * 1048576;
    const int t  = threadIdx.x;
    const int n0 = blockIdx.x * 64;
    const int k0 = blockIdx.y * 64;
    const int r  = t >> 2;
    const int c4 = (t & 3) * 16;
    #pragma unroll
    for (int j = 0; j < 4; ++j) {
        float4 v = *(const float4*)&w[(size_t)(k0 + r) * 1024 + n0 + c4 + j * 4];
        tile[r][c4 + j * 4 + 0] = v.x; tile[r][c4 + j * 4 + 1] = v.y;
        tile[r][c4 + j * 4 + 2] = v.z; tile[r][c4 + j * 4 + 3] = v.w;
    }
    __syncthreads();
    const int nn = t >> 2;
    const int kc = (t & 3) * 16;
    ushort8 o0, o1;
    #pragma unroll
    for (int j = 0; j < 8; ++j) o0[j] = f2bf(tile[kc + j][nn]);
    #pragma unroll
    for (int j = 0; j < 8; ++j) o1[j] = f2bf(tile[kc + 8 + j][nn]);
    *(ushort8*)&dst[(size_t)(n0 + nn) * 1024 + k0 + kc]     = o0;
    *(ushort8*)&dst[(size_t)(n0 + nn) * 1024 + k0 + kc + 8] = o1;
}

// ---------------------------------------------------------------------------
// Phase A: fused QKV.  BM=256, BN=64 per matrix, BK=64, 8 waves (4m x 2n).
// 2 phases per K-tile, 24 MFMA/phase; A double-buffered, B triple-buffered.
// ---------------------------------------------------------------------------
__global__ __launch_bounds__(512) void qkv_mfma(
    const unsigned short* __restrict__ xb,       // half: [16384,1024] bf16
    const unsigned short* __restrict__ wqT,
    const unsigned short* __restrict__ wkT,
    const unsigned short* __restrict__ wvT,
    const float* __restrict__ bq, const float* __restrict__ bk,
    const float* __restrict__ bv,
    unsigned short* __restrict__ Qout,           // full [32768,1024]
    float* __restrict__ KV, float* __restrict__ Ks,
    int moff)
{
    __shared__ unsigned short Alds[2][256 * 64];     // 64 KB
    __shared__ unsigned short Blds[3][3][64 * 64];   // 72 KB  [buf][mat]
    __shared__ float redkv[16][64];
    __shared__ float redks[16][64];

    const int t    = threadIdx.x;
    const int h0   = blockIdx.x * 64;
    const int m0   = blockIdx.y * 256;
    const int mg   = moff + m0;
    const int bidx = mg >> 13;

    const int lane = t & 63, wid = t >> 6;
    const int wm = wid >> 1, wn = wid & 1;
    const int lr = lane & 15, quad = lane >> 4;

    const int sA   = wid * 64 + lane;
    const int xks0 = ((quad)     ^ (lr & 7)) * 8;
    const int xks1 = ((quad | 4) ^ (lr & 7)) * 8;
    const int arow = (wm * 64 + lr) * 64;
    const int brow = (wn * 32 + lr) * 64;

    // A unit u = 64 rows (512 chunks); all 8 waves issue 1 glds each.
    auto stA = [&](int kt, int u, int buf) {
        const int s = u * 512 + sA;
        const int r = s >> 3;
        const int j = (s & 7) ^ (r & 7);
        glds16(&xb[(size_t)(m0 + r) * 1024 + kt * 64 + j * 8],
               &Alds[buf][(u * 512 + wid * 64) * 8]);
    };
    // B matrix tile = 64 rows = 1 unit.
    auto stB = [&](const unsigned short* w, int mat, int kt, int buf) {
        const int r = sA >> 3;
        const int j = (sA & 7) ^ (r & 7);
        glds16(&w[(size_t)(h0 + r) * 1024 + kt * 64 + j * 8],
               &Blds[buf][mat][wid * 512]);
    };

    f32x4 accq[4][2], acck[4][2], accv[4][2];
    #pragma unroll
    for (int mi = 0; mi < 4; ++mi)
        #pragma unroll
        for (int nj = 0; nj < 2; ++nj) {
            accq[mi][nj] = (f32x4){0.f, 0.f, 0.f, 0.f};
            acck[mi][nj] = (f32x4){0.f, 0.f, 0.f, 0.f};
            accv[mi][nj] = (f32x4){0.f, 0.f, 0.f, 0.f};
        }

    // prologue: A(0) 4u -> abuf0, B(0) -> bbuf0, B(1) -> bbuf1
    #pragma unroll
    for (int u = 0; u < 4; ++u) stA(0, u, 0);
    stB(wqT, 0, 0, 0); stB(wkT, 1, 0, 0); stB(wvT, 2, 0, 0);
    stB(wqT, 0, 1, 1); stB(wkT, 1, 1, 1); stB(wvT, 2, 1, 1);
    VM3();                                   // drain A(0),B(0); keep B(1)
    KBAR();

#define QKV_PH(AB, BB, XK, STG, WT)                                             \
    {                                                                           \
        bf16x8 af[4], bmat[3][2];                                               \
        _Pragma("unroll")                                                       \
        for (int mi = 0; mi < 4; ++mi)                                          \
            af[mi] = LDF(Alds[AB], arow + mi * 1024 + (XK));                    \
        _Pragma("unroll")                                                       \
        for (int mt = 0; mt < 3; ++mt)                                          \
            _Pragma("unroll")                                                   \
            for (int nj = 0; nj < 2; ++nj)                                      \
                bmat[mt][nj] = LDF(Blds[BB][mt], brow + nj * 1024 + (XK));      \
        STG;                                                                    \
        KBAR();                                                                 \
        LGKM0();                                                                \
        __builtin_amdgcn_s_setprio(1);                                          \
        _Pragma("unroll")                                                       \
        for (int mi = 0; mi < 4; ++mi)                                          \
            _Pragma("unroll")                                                   \
            for (int nj = 0; nj < 2; ++nj) {                                    \
                accq[mi][nj] = __builtin_amdgcn_mfma_f32_16x16x32_bf16(af[mi], bmat[0][nj], accq[mi][nj], 0, 0, 0); \
                acck[mi][nj] = __builtin_amdgcn_mfma_f32_16x16x32_bf16(af[mi], bmat[1][nj], acck[mi][nj], 0, 0, 0); \
                accv[mi][nj] = __builtin_amdgcn_mfma_f32_16x16x32_bf16(af[mi], bmat[2][nj], accv[mi][nj], 0, 0, 0); \
            }                                                                   \
        __builtin_amdgcn_s_setprio(0);                                          \
        WT;                                                                     \
        KBAR();                                                                 \
    }

    #pragma unroll
    for (int kt = 0; kt < 16; ++kt) {
        const int ab  = kt & 1;
        const int bb  = kt % 3;
        const int nab = (kt + 1) & 1;
        const int nbb = (kt + 2) % 3;
        // even phase: stage all 4 A(kt+1) units (A buf[nab] free since the
        // previous tile's closing barrier)
        QKV_PH(ab, bb, xks0,
               { if (kt < 15) { stA(kt + 1, 0, nab); stA(kt + 1, 1, nab);
                                stA(kt + 1, 2, nab); stA(kt + 1, 3, nab); } },
               {});
        // odd phase: stage B(kt+2) (its buf was last read at tile kt-1);
        // vmcnt(3) keeps B(kt+2) in flight, drains A(kt+1)+B(kt+1)
        if (kt <= 13) {
            QKV_PH(ab, bb, xks1,
                   { stB(wqT, 0, kt + 2, nbb); stB(wkT, 1, kt + 2, nbb);
                     stB(wvT, 2, kt + 2, nbb); },
                   VM3());
        } else if (kt == 14) {
            QKV_PH(ab, bb, xks1, {}, VM0());
        } else {
            QKV_PH(ab, bb, xks1, {}, {});
        }
    }
#undef QKV_PH

    // ---- epilogue: bias, elu+1, Q store (bf16), KV/Ksum partials ----
    float bqv[2], bkv[2], bvv[2];
    #pragma unroll
    for (int nj = 0; nj < 2; ++nj) {
        const int h = h0 + wn * 32 + nj * 16 + lr;
        bqv[nj] = bq[h]; bkv[nj] = bk[h]; bvv[nj] = bv[h];
    }
    float kvp[2] = {0.f, 0.f}, ksp[2] = {0.f, 0.f};
    #pragma unroll
    for (int mi = 0; mi < 4; ++mi)
        #pragma unroll
        for (int nj = 0; nj < 2; ++nj) {
            const int h = h0 + wn * 32 + nj * 16 + lr;
            #pragma unroll
            for (int r = 0; r < 4; ++r) {
                const int m = mg + wm * 64 + mi * 16 + quad * 4 + r;
                float q = elu1(accq[mi][nj][r] + bqv[nj]);
                Qout[(size_t)m * 1024 + h] = f2bf(q);
                float kk = elu1(acck[mi][nj][r] + bkv[nj]);
                float vv = accv[mi][nj][r] + bvv[nj];
                kvp[nj] = fmaf(kk, vv, kvp[nj]);
                ksp[nj] += kk;
            }
        }
    #pragma unroll
    for (int nj = 0; nj < 2; ++nj) {
        redkv[wm * 4 + quad][wn * 32 + nj * 16 + lr] = kvp[nj];
        redks[wm * 4 + quad][wn * 32 + nj * 16 + lr] = ksp[nj];
    }
    __syncthreads();
    if (t < 64) {
        float s = 0.f;
        #pragma unroll
        for (int g = 0; g < 16; ++g) s += redkv[g][t];
        atomicAdd(&KV[bidx * 1024 + h0 + t], s);
    } else if (t < 128) {
        const int c = t - 64;
        float s = 0.f;
        #pragma unroll
        for (int g = 0; g < 16; ++g) s += redks[g][c];
        atomicAdd(&Ks[bidx * 1024 + h0 + c], s);
    }
}

// ---------------------------------------------------------------------------
// V' = Q*KV / (Q*Ksum + 1e-6), elementwise in-place on Q (bf16)
// ---------------------------------------------------------------------------
__global__ __launch_bounds__(256) void vprime(
    unsigned short* __restrict__ Q,
    const float* __restrict__ KV, const float* __restrict__ Ks)
{
    const size_t idx  = (size_t)blockIdx.x * 256 + threadIdx.x;
    const size_t base = idx * 8;
    const int h = (int)(base & 1023);
    const int n = (int)(base >> 23);
    ushort8 q8 = *(ushort8*)&Q[base];
    const float* kvp = &KV[n * 1024 + h];
    const float* ksp = &Ks[n * 1024 + h];
    ushort8 o;
    #pragma unroll
    for (int j = 0; j < 8; ++j) {
        float qf = bf2f(q8[j]);
        float vp = qf * kvp[j] * __builtin_amdgcn_rcpf(fmaf(qf, ksp[j], 1e-6f));
        o[j] = f2bf(vp);
    }
    *(ushort8*)&Q[base] = o;
}

// ---------------------------------------------------------------------------
// Phase B: out = gelu(V' @ wo + bo).  256x256 tile, BK=64, 8 waves (2m x 4n),
// snake-quadrant 8-phase schedule, 16 MFMA/phase, LDS 128KB.  (unchanged)
// ---------------------------------------------------------------------------
__global__ __launch_bounds__(512) void out_mfma(
    const unsigned short* __restrict__ Vp,
    const unsigned short* __restrict__ woT,
    const float* __restrict__ bo, float* __restrict__ out)
{
    __shared__ unsigned short Alds[2][256 * 64];   // 64 KB
    __shared__ unsigned short Blds[2][256 * 64];   // 64 KB

    const int t  = threadIdx.x;
    const int h0 = blockIdx.x * 256;
    const int m0 = blockIdx.y * 256;

    const int lane = t & 63, wid = t >> 6;
    const int wm = wid >> 2, wn = wid & 3;
    const int lr = lane & 15, quad = lane >> 4;

    const int sA   = wid * 64 + lane;
    const int xks0 = ((quad)     ^ (lr & 7)) * 8;
    const int xks1 = ((quad | 4) ^ (lr & 7)) * 8;
    const int arow = (wm * 128 + lr) * 64;
    const int brow = (wn * 64 + lr) * 64;

    auto stA = [&](int kt, int u, int buf) {
        const int s = u * 512 + sA;
        const int r = s >> 3;
        const int j = (s & 7) ^ (r & 7);
        glds16(&Vp[(size_t)(m0 + r) * 1024 + kt * 64 + j * 8],
               &Alds[buf][(u * 512 + wid * 64) * 8]);
    };
    auto stB = [&](int kt, int u, int buf) {
        const int s = u * 512 + sA;
        const int r = s >> 3;
        const int j = (s & 7) ^ (r & 7);
        glds16(&woT[(size_t)(h0 + r) * 1024 + kt * 64 + j * 8],
               &Blds[buf][(u * 512 + wid * 64) * 8]);
    };

    f32x4 acc[8][4];
    #pragma unroll
    for (int mr = 0; mr < 8; ++mr)
        #pragma unroll
        for (int nc = 0; nc < 4; ++nc) acc[mr][nc] = (f32x4){0.f, 0.f, 0.f, 0.f};

    // prologue
    #pragma unroll
    for (int u = 0; u < 4; ++u) stA(0, u, 0);
    #pragma unroll
    for (int u = 0; u < 4; ++u) stB(0, u, 0);
    stA(1, 0, 1); stA(1, 1, 1);
    VM2();
    KBAR();

    bf16x8 af[4][2], bf_[2][2];

#define OUT_LDA(BUF, MH)                                                        \
    {                                                                           \
        _Pragma("unroll")                                                       \
        for (int mi = 0; mi < 4; ++mi) {                                        \
            af[mi][0] = __builtin_bit_cast(bf16x8,                              \
                *(const ushort8*)&Alds[BUF][arow + (MH) * 4096 + mi * 1024 + xks0]); \
            af[mi][1] = __builtin_bit_cast(bf16x8,                              \
                *(const ushort8*)&Alds[BUF][arow + (MH) * 4096 + mi * 1024 + xks1]); \
        }                                                                       \
    }

#define OUT_LDB(BUF, NH)                                                        \
    {                                                                           \
        _Pragma("unroll")                                                       \
        for (int nj = 0; nj < 2; ++nj) {                                        \
            bf_[nj][0] = __builtin_bit_cast(bf16x8,                             \
                *(const ushort8*)&Blds[BUF][brow + (NH) * 2048 + nj * 1024 + xks0]); \
            bf_[nj][1] = __builtin_bit_cast(bf16x8,                             \
                *(const ushort8*)&Blds[BUF][brow + (NH) * 2048 + nj * 1024 + xks1]); \
        }                                                                       \
    }

#define OUT_PHASE(MH, NH, STG, WT)                                              \
    {                                                                           \
        STG;                                                                    \
        KBAR();                                                                 \
        LGKM0();                                                                \
        __builtin_amdgcn_s_setprio(1);                                          \
        _Pragma("unroll")                                                       \
        for (int mi = 0; mi < 4; ++mi)                                          \
            _Pragma("unroll")                                                   \
            for (int nj = 0; nj < 2; ++nj) {                                    \
                acc[(MH) * 4 + mi][(NH) * 2 + nj] = __builtin_amdgcn_mfma_f32_16x16x32_bf16( \
                    af[mi][0], bf_[nj][0], acc[(MH) * 4 + mi][(NH) * 2 + nj], 0, 0, 0); \
                acc[(MH) * 4 + mi][(NH) * 2 + nj] = __builtin_amdgcn_mfma_f32_16x16x32_bf16( \
                    af[mi][1], bf_[nj][1], acc[(MH) * 4 + mi][(NH) * 2 + nj], 0, 0, 0); \
            }                                                                   \
        __builtin_amdgcn_s_setprio(0);                                          \
        WT;                                                                     \
        KBAR();                                                                 \
    }

    for (int i = 0; i < 8; ++i) {
        const int t1 = 2 * i + 1;
        // ---- tile 2i (buf 0), snake: (0,0) (0,1) (1,1) (1,0) ----
        OUT_LDA(0, 0); OUT_LDB(0, 0);                                          // P1
        OUT_PHASE(0, 0, { stA(t1, 2, 1); stA(t1, 3, 1); }, {});
        OUT_LDB(0, 1);                                                         // P2
        OUT_PHASE(0, 1, { stB(t1, 0, 1); stB(t1, 1, 1); }, {});
        OUT_LDA(0, 1);                                                         // P3
        OUT_PHASE(1, 1, { stB(t1, 2, 1); stB(t1, 3, 1); }, {});
        OUT_LDB(0, 0);                                                         // P4
        if (i < 7) {
            OUT_PHASE(1, 0, { stA(t1 + 1, 0, 0); stA(t1 + 1, 1, 0); }, VM2());
        } else {
            OUT_PHASE(1, 0, {}, VM0());
        }
        // ---- tile 2i+1 (buf 1) ----
        OUT_LDA(1, 0); OUT_LDB(1, 0);                                          // P5
        if (i < 7) {
            OUT_PHASE(0, 0, { stA(t1 + 1, 2, 0); stA(t1 + 1, 3, 0); }, {});
            OUT_LDB(1, 1);                                                     // P6
            OUT_PHASE(0, 1, { stB(t1 + 1, 0, 0); stB(t1 + 1, 1, 0); }, {});
            OUT_LDA(1, 1);                                                     // P7
            OUT_PHASE(1, 1, { stB(t1 + 1, 2, 0); stB(t1 + 1, 3, 0); }, {});
            OUT_LDB(1, 0);                                                     // P8
            OUT_PHASE(1, 0, { stA(t1 + 2, 0, 1); stA(t1 + 2, 1, 1); }, VM2());
        } else {
            OUT_PHASE(0, 0, {}, {});
            OUT_LDB(1, 1);
            OUT_PHASE(0, 1, {}, {});
            OUT_LDA(1, 1);
            OUT_PHASE(1, 1, {}, {});
            OUT_LDB(1, 0);
            OUT_PHASE(1, 0, {}, {});
        }
    }
#undef OUT_LDA
#undef OUT_LDB
#undef OUT_PHASE

    float bov[4];
    #pragma unroll
    for (int nc = 0; nc < 4; ++nc) bov[nc] = bo[h0 + wn * 64 + nc * 16 + lr];
    #pragma unroll
    for (int mr = 0; mr < 8; ++mr)
        #pragma unroll
        for (int nc = 0; nc < 4; ++nc) {
            const int h = h0 + wn * 64 + nc * 16 + lr;
            #pragma unroll
            for (int r = 0; r < 4; ++r) {
                const int m = m0 + wm * 128 + mr * 16 + quad * 4 + r;
                out[(size_t)m * 1024 + h] = gelu_tanh(acc[mr][nc][r] + bov[nc]);
            }
        }
}

extern "C" void kernel_launch(void* const* d_in, const int* in_sizes, int n_in,
                              void* d_out, int out_size, void* d_ws, size_t ws_size,
                              hipStream_t stream)
{
    const float* x  = (const float*)d_in[0];
    const float* wq = (const float*)d_in[1];
    const float* bq = (const float*)d_in[2];
    const float* wk = (const float*)d_in[3];
    const float* bk = (const float*)d_in[4];
    const float* wv = (const float*)d_in[5];
    const float* bv = (const float*)d_in[6];
    const float* wo = (const float*)d_in[7];
    const float* bo = (const float*)d_in[8];
    float* out = (float*)d_out;

    // ws layout (bytes):
    //   [0, 64M)        Q / V' bf16  (32768 x 1024)
    //   [64M, 96M)      xb bf16 half (16384 x 1024), reused for both halves
    //   [96M, 104M)     wqT, wkT, wvT, woT bf16 (2MB each, contiguous)
    //   [104M, ...)     KV fp32 [4,1024], Ks fp32 [4,1024]
    char* wsb = (char*)d_ws;
    unsigned short* Qws = (unsigned short*)wsb;
    unsigned short* xb  = (unsigned short*)(wsb + 67108864ULL);
    unsigned short* wqT = (unsigned short*)(wsb + 100663296ULL);
    unsigned short* wkT = wqT + 1048576;
    unsigned short* wvT = wkT + 1048576;
    unsigned short* woT = wvT + 1048576;
    float* KV = (float*)(wsb + 100663296ULL + 4ULL * 2097152);
    float* Ks = KV + 4 * 1024;

    hipMemsetAsync(KV, 0, 2 * 4 * 1024 * sizeof(float), stream);

    wtrans<<<dim3(16, 16, 4), 256, 0, stream>>>(wq, wk, wv, wo, wqT);

    for (int half = 0; half < 2; ++half) {
        xconv<<<8192, 256, 0, stream>>>(x + (size_t)half * 16384 * 1024, xb);
        qkv_mfma<<<dim3(16, 64), 512, 0, stream>>>(xb, wqT, wkT, wvT, bq, bk, bv,
                                                   Qws, KV, Ks, half * 16384);
    }
    vprime<<<16384, 256, 0, stream>>>(Qws, KV, Ks);
    out_mfma<<<dim3(4, 128), 512, 0, stream>>>(Qws, woT, bo, out);
}

// Round 3
// 524.697 us; speedup vs baseline: 1.0977x; 1.0041x over previous
//
#include <hip/hip_runtime.h>
#include <math.h>
#include <stdint.h>

// LinearAttention  N=4, S=8192, D_IN=1024, ATTN_DIM=1024, OUT_DIM=1024
// R7: qkv deep prefetch + XCD swizzle.
//  - A triple-buffered (3x32KB), staged 2 tiles ahead (~3 phases ~3000cyc
//    slack vs R6's 1 phase); B double-buffered, staged 1 tile ahead, issued
//    BEFORE A in the even phase so a single vmcnt(4) at odd-phase end drains
//    A(t+1)+B(t+1) while keeping A(t+2) in flight.  LDS 152KB.
//  - bijective XCD swizzle on qkv (chunk 128) and out (chunk 64): all 16
//    h-blocks sharing an A-row run on ONE XCD -> A fetched once per L2
//    (R6 FETCH 143MB ~= 4x over-fetch of the 32MB xb half).
// out_mfma structure unchanged (256^2 8-phase template) + swizzle.
// Numerics identical to R6.

#define S_LEN 8192

typedef __attribute__((ext_vector_type(8))) __bf16 bf16x8;
typedef __attribute__((ext_vector_type(8))) unsigned short ushort8;
typedef __attribute__((ext_vector_type(4))) float f32x4;

__device__ __forceinline__ unsigned short f2bf(float f) {
    unsigned int u = __builtin_bit_cast(unsigned int, f);
    unsigned int r = (u + 0x7fffu + ((u >> 16) & 1u)) >> 16;   // RNE
    return (unsigned short)r;
}
__device__ __forceinline__ float bf2f(unsigned short s) {
    unsigned int u = ((unsigned int)s) << 16;
    return __builtin_bit_cast(float, u);
}
__device__ __forceinline__ float elu1(float v) { return v > 0.f ? v + 1.f : __expf(v); }
__device__ __forceinline__ float gelu_tanh(float v) {
    float u = 1.5957691216057308f * (v + 0.044715f * v * v * v);
    float e = __expf(u);
    float th = 1.f - 2.f / (e + 1.f);
    return 0.5f * v * (1.f + th);
}
__device__ __forceinline__ void glds16(const void* g, void* l) {
    __builtin_amdgcn_global_load_lds(
        (const __attribute__((address_space(1))) unsigned int*)(uintptr_t)g,
        (__attribute__((address_space(3))) unsigned int*)(uintptr_t)l, 16, 0, 0);
}

#define KBAR()  asm volatile("s_barrier" ::: "memory")
#define LGKM0() do { asm volatile("s_waitcnt lgkmcnt(0)" ::: "memory"); \
                     __builtin_amdgcn_sched_barrier(0); } while (0)
#define VM4()   asm volatile("s_waitcnt vmcnt(4)" ::: "memory")
#define VM2()   asm volatile("s_waitcnt vmcnt(2)" ::: "memory")
#define VM0()   asm volatile("s_waitcnt vmcnt(0)" ::: "memory")

#define LDF(P, OFF) __builtin_bit_cast(bf16x8, *(const ushort8*)&(P)[OFF])

// ---------------------------------------------------------------------------
// x fp32 -> bf16, one half (16384 rows) per call
// ---------------------------------------------------------------------------
__global__ __launch_bounds__(256) void xconv(const float* __restrict__ x,
                                             unsigned short* __restrict__ xb)
{
    const size_t base = ((size_t)blockIdx.x * 256 + threadIdx.x) * 8;
    float4 a = *(const float4*)&x[base];
    float4 b = *(const float4*)&x[base + 4];
    ushort8 o;
    o[0] = f2bf(a.x); o[1] = f2bf(a.y); o[2] = f2bf(a.z); o[3] = f2bf(a.w);
    o[4] = f2bf(b.x); o[5] = f2bf(b.y); o[6] = f2bf(b.z); o[7] = f2bf(b.w);
    *(ushort8*)&xb[base] = o;
}

// ---------------------------------------------------------------------------
// weight transpose + convert, all 4 matrices in one launch (blockIdx.z)
// ---------------------------------------------------------------------------
__global__ __launch_bounds__(256) void wtrans(const float* __restrict__ wq,
                                              const float* __restrict__ wk,
                                              const float* __restrict__ wv,
                                              const float* __restrict__ wo,
                                              unsigned short* __restrict__ wT)
{
    __shared__ float tile[64][65];
    const int z = blockIdx.z;
    const float* w = (z == 0) ? wq : (z == 1) ? wk : (z == 2) ? wv : wo;
    unsigned short* dst = wT + (size_t)z * 1048576;
    const int t  = threadIdx.x;
    const int n0 = blockIdx.x * 64;
    const int k0 = blockIdx.y * 64;
    const int r  = t >> 2;
    const int c4 = (t & 3) * 16;
    #pragma unroll
    for (int j = 0; j < 4; ++j) {
        float4 v = *(const float4*)&w[(size_t)(k0 + r) * 1024 + n0 + c4 + j * 4];
        tile[r][c4 + j * 4 + 0] = v.x; tile[r][c4 + j * 4 + 1] = v.y;
        tile[r][c4 + j * 4 + 2] = v.z; tile[r][c4 + j * 4 + 3] = v.w;
    }
    __syncthreads();
    const int nn = t >> 2;
    const int kc = (t & 3) * 16;
    ushort8 o0, o1;
    #pragma unroll
    for (int j = 0; j < 8; ++j) o0[j] = f2bf(tile[kc + j][nn]);
    #pragma unroll
    for (int j = 0; j < 8; ++j) o1[j] = f2bf(tile[kc + 8 + j][nn]);
    *(ushort8*)&dst[(size_t)(n0 + nn) * 1024 + k0 + kc]     = o0;
    *(ushort8*)&dst[(size_t)(n0 + nn) * 1024 + k0 + kc + 8] = o1;
}

// ---------------------------------------------------------------------------
// Phase A: fused QKV.  BM=256, BN=64 per matrix, BK=64, 8 waves (4m x 2n).
// 2 phases per K-tile, 24 MFMA/phase.  A tbuf staged 2 ahead, B dbuf staged
// 1 ahead (issued before A), vmcnt(4) at odd-phase end.  XCD swizzle.
// ---------------------------------------------------------------------------
__global__ __launch_bounds__(512) void qkv_mfma(
    const unsigned short* __restrict__ xb,       // half: [16384,1024] bf16
    const unsigned short* __restrict__ wqT,
    const unsigned short* __restrict__ wkT,
    const unsigned short* __restrict__ wvT,
    const float* __restrict__ bq, const float* __restrict__ bk,
    const float* __restrict__ bv,
    unsigned short* __restrict__ Qout,           // full [32768,1024]
    float* __restrict__ KV, float* __restrict__ Ks,
    int moff)
{
    __shared__ unsigned short Alds[3][256 * 64];     // 96 KB
    __shared__ unsigned short Blds[2][3][64 * 64];   // 48 KB  [buf][mat]
    __shared__ float redkv[16][64];
    __shared__ float redks[16][64];

    const int t = threadIdx.x;
    // bijective XCD swizzle: 1024 blocks, 8 XCDs, chunk 128.  XCD k owns
    // m-blocks [k*8,(k+1)*8) x all 16 h-blocks -> each A-row hits one L2.
    const unsigned int nlin = blockIdx.x + 16u * blockIdx.y;
    const unsigned int swz  = (nlin & 7u) * 128u + (nlin >> 3);
    const int h0   = (int)(swz & 15u) * 64;
    const int m0   = (int)(swz >> 4) * 256;
    const int mg   = moff + m0;
    const int bidx = mg >> 13;

    const int lane = t & 63, wid = t >> 6;
    const int wm = wid >> 1, wn = wid & 1;
    const int lr = lane & 15, quad = lane >> 4;

    const int sA   = wid * 64 + lane;
    const int xks0 = ((quad)     ^ (lr & 7)) * 8;
    const int xks1 = ((quad | 4) ^ (lr & 7)) * 8;
    const int arow = (wm * 64 + lr) * 64;
    const int brow = (wn * 32 + lr) * 64;

    // A unit u = 64 rows (512 chunks); all 8 waves issue 1 glds each.
    auto stA = [&](int kt, int u, int buf) {
        const int s = u * 512 + sA;
        const int r = s >> 3;
        const int j = (s & 7) ^ (r & 7);
        glds16(&xb[(size_t)(m0 + r) * 1024 + kt * 64 + j * 8],
               &Alds[buf][(u * 512 + wid * 64) * 8]);
    };
    // B matrix tile = 64 rows = 1 unit.
    auto stB = [&](const unsigned short* w, int mat, int kt, int buf) {
        const int r = sA >> 3;
        const int j = (sA & 7) ^ (r & 7);
        glds16(&w[(size_t)(h0 + r) * 1024 + kt * 64 + j * 8],
               &Blds[buf][mat][wid * 512]);
    };

    f32x4 accq[4][2], acck[4][2], accv[4][2];
    #pragma unroll
    for (int mi = 0; mi < 4; ++mi)
        #pragma unroll
        for (int nj = 0; nj < 2; ++nj) {
            accq[mi][nj] = (f32x4){0.f, 0.f, 0.f, 0.f};
            acck[mi][nj] = (f32x4){0.f, 0.f, 0.f, 0.f};
            accv[mi][nj] = (f32x4){0.f, 0.f, 0.f, 0.f};
        }

    // prologue: A(0)->abuf0, B(0)->bbuf0, A(1)->abuf1; drain A(0),B(0)
    #pragma unroll
    for (int u = 0; u < 4; ++u) stA(0, u, 0);
    stB(wqT, 0, 0, 0); stB(wkT, 1, 0, 0); stB(wvT, 2, 0, 0);
    #pragma unroll
    for (int u = 0; u < 4; ++u) stA(1, u, 1);
    VM4();                                   // keep A(1), drain A(0)+B(0)
    KBAR();

#define QKV_PH(AB, BB, XK, STG, WT)                                             \
    {                                                                           \
        bf16x8 af[4], bmat[3][2];                                               \
        _Pragma("unroll")                                                       \
        for (int mi = 0; mi < 4; ++mi)                                          \
            af[mi] = LDF(Alds[AB], arow + mi * 1024 + (XK));                    \
        _Pragma("unroll")                                                       \
        for (int mt = 0; mt < 3; ++mt)                                          \
            _Pragma("unroll")                                                   \
            for (int nj = 0; nj < 2; ++nj)                                      \
                bmat[mt][nj] = LDF(Blds[BB][mt], brow + nj * 1024 + (XK));      \
        STG;                                                                    \
        KBAR();                                                                 \
        LGKM0();                                                                \
        __builtin_amdgcn_s_setprio(1);                                          \
        _Pragma("unroll")                                                       \
        for (int mi = 0; mi < 4; ++mi)                                          \
            _Pragma("unroll")                                                   \
            for (int nj = 0; nj < 2; ++nj) {                                    \
                accq[mi][nj] = __builtin_amdgcn_mfma_f32_16x16x32_bf16(af[mi], bmat[0][nj], accq[mi][nj], 0, 0, 0); \
                acck[mi][nj] = __builtin_amdgcn_mfma_f32_16x16x32_bf16(af[mi], bmat[1][nj], acck[mi][nj], 0, 0, 0); \
                accv[mi][nj] = __builtin_amdgcn_mfma_f32_16x16x32_bf16(af[mi], bmat[2][nj], accv[mi][nj], 0, 0, 0); \
            }                                                                   \
        __builtin_amdgcn_s_setprio(0);                                          \
        WT;                                                                     \
        KBAR();                                                                 \
    }

    #pragma unroll
    for (int kt = 0; kt < 16; ++kt) {
        const int ab = kt % 3;
        const int bb = kt & 1;
        // even phase: stage B(kt+1) FIRST (older in FIFO), then A(kt+2)
        QKV_PH(ab, bb, xks0,
               {
                   if (kt + 1 < 16) {
                       stB(wqT, 0, kt + 1, (kt + 1) & 1);
                       stB(wkT, 1, kt + 1, (kt + 1) & 1);
                       stB(wvT, 2, kt + 1, (kt + 1) & 1);
                   }
                   if (kt + 2 < 16) {
                       stA(kt + 2, 0, (kt + 2) % 3); stA(kt + 2, 1, (kt + 2) % 3);
                       stA(kt + 2, 2, (kt + 2) % 3); stA(kt + 2, 3, (kt + 2) % 3);
                   }
               },
               {});
        // odd phase: vmcnt(4) keeps A(kt+2) in flight, drains A(kt+1)+B(kt+1)
        if (kt <= 13) {
            QKV_PH(ab, bb, xks1, {}, VM4());
        } else if (kt == 14) {
            QKV_PH(ab, bb, xks1, {}, VM0());
        } else {
            QKV_PH(ab, bb, xks1, {}, {});
        }
    }
#undef QKV_PH

    // ---- epilogue: bias, elu+1, Q store (bf16), KV/Ksum partials ----
    float bqv[2], bkv[2], bvv[2];
    #pragma unroll
    for (int nj = 0; nj < 2; ++nj) {
        const int h = h0 + wn * 32 + nj * 16 + lr;
        bqv[nj] = bq[h]; bkv[nj] = bk[h]; bvv[nj] = bv[h];
    }
    float kvp[2] = {0.f, 0.f}, ksp[2] = {0.f, 0.f};
    #pragma unroll
    for (int mi = 0; mi < 4; ++mi)
        #pragma unroll
        for (int nj = 0; nj < 2; ++nj) {
            const int h = h0 + wn * 32 + nj * 16 + lr;
            #pragma unroll
            for (int r = 0; r < 4; ++r) {
                const int m = mg + wm * 64 + mi * 16 + quad * 4 + r;
                float q = elu1(accq[mi][nj][r] + bqv[nj]);
                Qout[(size_t)m * 1024 + h] = f2bf(q);
                float kk = elu1(acck[mi][nj][r] + bkv[nj]);
                float vv = accv[mi][nj][r] + bvv[nj];
                kvp[nj] = fmaf(kk, vv, kvp[nj]);
                ksp[nj] += kk;
            }
        }
    #pragma unroll
    for (int nj = 0; nj < 2; ++nj) {
        redkv[wm * 4 + quad][wn * 32 + nj * 16 + lr] = kvp[nj];
        redks[wm * 4 + quad][wn * 32 + nj * 16 + lr] = ksp[nj];
    }
    __syncthreads();
    if (t < 64) {
        float s = 0.f;
        #pragma unroll
        for (int g = 0; g < 16; ++g) s += redkv[g][t];
        atomicAdd(&KV[bidx * 1024 + h0 + t], s);
    } else if (t < 128) {
        const int c = t - 64;
        float s = 0.f;
        #pragma unroll
        for (int g = 0; g < 16; ++g) s += redks[g][c];
        atomicAdd(&Ks[bidx * 1024 + h0 + c], s);
    }
}

// ---------------------------------------------------------------------------
// V' = Q*KV / (Q*Ksum + 1e-6), elementwise in-place on Q (bf16)
// ---------------------------------------------------------------------------
__global__ __launch_bounds__(256) void vprime(
    unsigned short* __restrict__ Q,
    const float* __restrict__ KV, const float* __restrict__ Ks)
{
    const size_t idx  = (size_t)blockIdx.x * 256 + threadIdx.x;
    const size_t base = idx * 8;
    const int h = (int)(base & 1023);
    const int n = (int)(base >> 23);
    ushort8 q8 = *(ushort8*)&Q[base];
    const float* kvp = &KV[n * 1024 + h];
    const float* ksp = &Ks[n * 1024 + h];
    ushort8 o;
    #pragma unroll
    for (int j = 0; j < 8; ++j) {
        float qf = bf2f(q8[j]);
        float vp = qf * kvp[j] * __builtin_amdgcn_rcpf(fmaf(qf, ksp[j], 1e-6f));
        o[j] = f2bf(vp);
    }
    *(ushort8*)&Q[base] = o;
}

// ---------------------------------------------------------------------------
// Phase B: out = gelu(V' @ wo + bo).  256x256 tile, BK=64, 8 waves (2m x 4n),
// snake-quadrant 8-phase schedule, 16 MFMA/phase, LDS 128KB.  + XCD swizzle.
// ---------------------------------------------------------------------------
__global__ __launch_bounds__(512) void out_mfma(
    const unsigned short* __restrict__ Vp,
    const unsigned short* __restrict__ woT,
    const float* __restrict__ bo, float* __restrict__ out)
{
    __shared__ unsigned short Alds[2][256 * 64];   // 64 KB
    __shared__ unsigned short Blds[2][256 * 64];   // 64 KB

    const int t  = threadIdx.x;
    // bijective XCD swizzle: 512 blocks, chunk 64 -> XCD k owns m-blocks
    // [k*16,(k+1)*16) x all 4 h-blocks.
    const unsigned int nlin = blockIdx.x + 4u * blockIdx.y;
    const unsigned int swz  = (nlin & 7u) * 64u + (nlin >> 3);
    const int h0 = (int)(swz & 3u) * 256;
    const int m0 = (int)(swz >> 2) * 256;

    const int lane = t & 63, wid = t >> 6;
    const int wm = wid >> 2, wn = wid & 3;
    const int lr = lane & 15, quad = lane >> 4;

    const int sA   = wid * 64 + lane;
    const int xks0 = ((quad)     ^ (lr & 7)) * 8;
    const int xks1 = ((quad | 4) ^ (lr & 7)) * 8;
    const int arow = (wm * 128 + lr) * 64;
    const int brow = (wn * 64 + lr) * 64;

    auto stA = [&](int kt, int u, int buf) {
        const int s = u * 512 + sA;
        const int r = s >> 3;
        const int j = (s & 7) ^ (r & 7);
        glds16(&Vp[(size_t)(m0 + r) * 1024 + kt * 64 + j * 8],
               &Alds[buf][(u * 512 + wid * 64) * 8]);
    };
    auto stB = [&](int kt, int u, int buf) {
        const int s = u * 512 + sA;
        const int r = s >> 3;
        const int j = (s & 7) ^ (r & 7);
        glds16(&woT[(size_t)(h0 + r) * 1024 + kt * 64 + j * 8],
               &Blds[buf][(u * 512 + wid * 64) * 8]);
    };

    f32x4 acc[8][4];
    #pragma unroll
    for (int mr = 0; mr < 8; ++mr)
        #pragma unroll
        for (int nc = 0; nc < 4; ++nc) acc[mr][nc] = (f32x4){0.f, 0.f, 0.f, 0.f};

    // prologue
    #pragma unroll
    for (int u = 0; u < 4; ++u) stA(0, u, 0);
    #pragma unroll
    for (int u = 0; u < 4; ++u) stB(0, u, 0);
    stA(1, 0, 1); stA(1, 1, 1);
    VM2();
    KBAR();

    bf16x8 af[4][2], bf_[2][2];

#define OUT_LDA(BUF, MH)                                                        \
    {                                                                           \
        _Pragma("unroll")                                                       \
        for (int mi = 0; mi < 4; ++mi) {                                        \
            af[mi][0] = __builtin_bit_cast(bf16x8,                              \
                *(const ushort8*)&Alds[BUF][arow + (MH) * 4096 + mi * 1024 + xks0]); \
            af[mi][1] = __builtin_bit_cast(bf16x8,                              \
                *(const ushort8*)&Alds[BUF][arow + (MH) * 4096 + mi * 1024 + xks1]); \
        }                                                                       \
    }

#define OUT_LDB(BUF, NH)                                                        \
    {                                                                           \
        _Pragma("unroll")                                                       \
        for (int nj = 0; nj < 2; ++nj) {                                        \
            bf_[nj][0] = __builtin_bit_cast(bf16x8,                             \
                *(const ushort8*)&Blds[BUF][brow + (NH) * 2048 + nj * 1024 + xks0]); \
            bf_[nj][1] = __builtin_bit_cast(bf16x8,                             \
                *(const ushort8*)&Blds[BUF][brow + (NH) * 2048 + nj * 1024 + xks1]); \
        }                                                                       \
    }

#define OUT_PHASE(MH, NH, STG, WT)                                              \
    {                                                                           \
        STG;                                                                    \
        KBAR();                                                                 \
        LGKM0();                                                                \
        __builtin_amdgcn_s_setprio(1);                                          \
        _Pragma("unroll")                                                       \
        for (int mi = 0; mi < 4; ++mi)                                          \
            _Pragma("unroll")                                                   \
            for (int nj = 0; nj < 2; ++nj) {                                    \
                acc[(MH) * 4 + mi][(NH) * 2 + nj] = __builtin_amdgcn_mfma_f32_16x16x32_bf16( \
                    af[mi][0], bf_[nj][0], acc[(MH) * 4 + mi][(NH) * 2 + nj], 0, 0, 0); \
                acc[(MH) * 4 + mi][(NH) * 2 + nj] = __builtin_amdgcn_mfma_f32_16x16x32_bf16( \
                    af[mi][1], bf_[nj][1], acc[(MH) * 4 + mi][(NH) * 2 + nj], 0, 0, 0); \
            }                                                                   \
        __builtin_amdgcn_s_setprio(0);                                          \
        WT;                                                                     \
        KBAR();                                                                 \
    }

    for (int i = 0; i < 8; ++i) {
        const int t1 = 2 * i + 1;
        // ---- tile 2i (buf 0), snake: (0,0) (0,1) (1,1) (1,0) ----
        OUT_LDA(0, 0); OUT_LDB(0, 0);                                          // P1
        OUT_PHASE(0, 0, { stA(t1, 2, 1); stA(t1, 3, 1); }, {});
        OUT_LDB(0, 1);                                                         // P2
        OUT_PHASE(0, 1, { stB(t1, 0, 1); stB(t1, 1, 1); }, {});
        OUT_LDA(0, 1);                                                         // P3
        OUT_PHASE(1, 1, { stB(t1, 2, 1); stB(t1, 3, 1); }, {});
        OUT_LDB(0, 0);                                                         // P4
        if (i < 7) {
            OUT_PHASE(1, 0, { stA(t1 + 1, 0, 0); stA(t1 + 1, 1, 0); }, VM2());
        } else {
            OUT_PHASE(1, 0, {}, VM0());
        }
        // ---- tile 2i+1 (buf 1) ----
        OUT_LDA(1, 0); OUT_LDB(1, 0);                                          // P5
        if (i < 7) {
            OUT_PHASE(0, 0, { stA(t1 + 1, 2, 0); stA(t1 + 1, 3, 0); }, {});
            OUT_LDB(1, 1);                                                     // P6
            OUT_PHASE(0, 1, { stB(t1 + 1, 0, 0); stB(t1 + 1, 1, 0); }, {});
            OUT_LDA(1, 1);                                                     // P7
            OUT_PHASE(1, 1, { stB(t1 + 1, 2, 0); stB(t1 + 1, 3, 0); }, {});
            OUT_LDB(1, 0);                                                     // P8
            OUT_PHASE(1, 0, { stA(t1 + 2, 0, 1); stA(t1 + 2, 1, 1); }, VM2());
        } else {
            OUT_PHASE(0, 0, {}, {});
            OUT_LDB(1, 1);
            OUT_PHASE(0, 1, {}, {});
            OUT_LDA(1, 1);
            OUT_PHASE(1, 1, {}, {});
            OUT_LDB(1, 0);
            OUT_PHASE(1, 0, {}, {});
        }
    }
#undef OUT_LDA
#undef OUT_LDB
#undef OUT_PHASE

    float bov[4];
    #pragma unroll
    for (int nc = 0; nc < 4; ++nc) bov[nc] = bo[h0 + wn * 64 + nc * 16 + lr];
    #pragma unroll
    for (int mr = 0; mr < 8; ++mr)
        #pragma unroll
        for (int nc = 0; nc < 4; ++nc) {
            const int h = h0 + wn * 64 + nc * 16 + lr;
            #pragma unroll
            for (int r = 0; r < 4; ++r) {
                const int m = m0 + wm * 128 + mr * 16 + quad * 4 + r;
                out[(size_t)m * 1024 + h] = gelu_tanh(acc[mr][nc][r] + bov[nc]);
            }
        }
}

extern "C" void kernel_launch(void* const* d_in, const int* in_sizes, int n_in,
                              void* d_out, int out_size, void* d_ws, size_t ws_size,
                              hipStream_t stream)
{
    const float* x  = (const float*)d_in[0];
    const float* wq = (const float*)d_in[1];
    const float* bq = (const float*)d_in[2];
    const float* wk = (const float*)d_in[3];
    const float* bk = (const float*)d_in[4];
    const float* wv = (const float*)d_in[5];
    const float* bv = (const float*)d_in[6];
    const float* wo = (const float*)d_in[7];
    const float* bo = (const float*)d_in[8];
    float* out = (float*)d_out;

    // ws layout (bytes):
    //   [0, 64M)        Q / V' bf16  (32768 x 1024)
    //   [64M, 96M)      xb bf16 half (16384 x 1024), reused for both halves
    //   [96M, 104M)     wqT, wkT, wvT, woT bf16 (2MB each, contiguous)
    //   [104M, ...)     KV fp32 [4,1024], Ks fp32 [4,1024]
    char* wsb = (char*)d_ws;
    unsigned short* Qws = (unsigned short*)wsb;
    unsigned short* xb  = (unsigned short*)(wsb + 67108864ULL);
    unsigned short* wqT = (unsigned short*)(wsb + 100663296ULL);
    unsigned short* wkT = wqT + 1048576;
    unsigned short* wvT = wkT + 1048576;
    unsigned short* woT = wvT + 1048576;
    float* KV = (float*)(wsb + 100663296ULL + 4ULL * 2097152);
    float* Ks = KV + 4 * 1024;

    hipMemsetAsync(KV, 0, 2 * 4 * 1024 * sizeof(float), stream);

    wtrans<<<dim3(16, 16, 4), 256, 0, stream>>>(wq, wk, wv, wo, wqT);

    for (int half = 0; half < 2; ++half) {
        xconv<<<8192, 256, 0, stream>>>(x + (size_t)half * 16384 * 1024, xb);
        qkv_mfma<<<dim3(16, 64), 512, 0, stream>>>(xb, wqT, wkT, wvT, bq, bk, bv,
                                                   Qws, KV, Ks, half * 16384);
    }
    vprime<<<16384, 256, 0, stream>>>(Qws, KV, Ks);
    out_mfma<<<dim3(4, 128), 512, 0, stream>>>(Qws, woT, bo, out);
}

// Round 4
// 516.980 us; speedup vs baseline: 1.1141x; 1.0149x over previous
//
#include <hip/hip_runtime.h>
#include <math.h>
#include <stdint.h>

// LinearAttention  N=4, S=8192, D_IN=1024, ATTN_DIM=1024, OUT_DIM=1024
// R8: single-barrier K-tiles + slice-overlapped reads.
// Measured model (R7): phase = MFMA-issue (~930cy) + EXPOSED ds_read drain
// (~900cy) + 2 barriers ~= 2095cy, because 2 lockstep waves/SIMD leave nobody
// to issue LDS reads during MFMA execution.  Fix: issue BOTH k-slices' ds_reads
// before the MFMA cluster; compiler's counted lgkmcnt lets ks1 reads drain on
// the LDS pipe while ks0 MFMAs occupy the matrix pipe.  One s_barrier per
// K-tile (16 total, was 32+).  Staging/vmcnt FIFO identical to R7 (A 3-buf
// 2-ahead, B 2-buf 1-ahead, vmcnt(4) steady, vmcnt(0) at kt=14).
// out_mfma gets the same structure (A 3-buf + B 2-buf = 160KB LDS exactly).
// VGPR is free (occupancy LDS-capped at 1 block/CU).  Numerics identical.

#define S_LEN 8192

typedef __attribute__((ext_vector_type(8))) __bf16 bf16x8;
typedef __attribute__((ext_vector_type(8))) unsigned short ushort8;
typedef __attribute__((ext_vector_type(4))) float f32x4;

__device__ __forceinline__ unsigned short f2bf(float f) {
    unsigned int u = __builtin_bit_cast(unsigned int, f);
    unsigned int r = (u + 0x7fffu + ((u >> 16) & 1u)) >> 16;   // RNE
    return (unsigned short)r;
}
__device__ __forceinline__ float bf2f(unsigned short s) {
    unsigned int u = ((unsigned int)s) << 16;
    return __builtin_bit_cast(float, u);
}
__device__ __forceinline__ float elu1(float v) { return v > 0.f ? v + 1.f : __expf(v); }
__device__ __forceinline__ float gelu_tanh(float v) {
    float u = 1.5957691216057308f * (v + 0.044715f * v * v * v);
    float e = __expf(u);
    float th = 1.f - 2.f / (e + 1.f);
    return 0.5f * v * (1.f + th);
}
__device__ __forceinline__ void glds16(const void* g, void* l) {
    __builtin_amdgcn_global_load_lds(
        (const __attribute__((address_space(1))) unsigned int*)(uintptr_t)g,
        (__attribute__((address_space(3))) unsigned int*)(uintptr_t)l, 16, 0, 0);
}

#define KBAR()  asm volatile("s_barrier" ::: "memory")
#define VM4()   asm volatile("s_waitcnt vmcnt(4)" ::: "memory")
#define VM0()   asm volatile("s_waitcnt vmcnt(0)" ::: "memory")

#define LDF(P, OFF) __builtin_bit_cast(bf16x8, *(const ushort8*)&(P)[OFF])

// ---------------------------------------------------------------------------
// x fp32 -> bf16, one half (16384 rows) per call
// ---------------------------------------------------------------------------
__global__ __launch_bounds__(256) void xconv(const float* __restrict__ x,
                                             unsigned short* __restrict__ xb)
{
    const size_t base = ((size_t)blockIdx.x * 256 + threadIdx.x) * 8;
    float4 a = *(const float4*)&x[base];
    float4 b = *(const float4*)&x[base + 4];
    ushort8 o;
    o[0] = f2bf(a.x); o[1] = f2bf(a.y); o[2] = f2bf(a.z); o[3] = f2bf(a.w);
    o[4] = f2bf(b.x); o[5] = f2bf(b.y); o[6] = f2bf(b.z); o[7] = f2bf(b.w);
    *(ushort8*)&xb[base] = o;
}

// ---------------------------------------------------------------------------
// weight transpose + convert, all 4 matrices in one launch (blockIdx.z)
// ---------------------------------------------------------------------------
__global__ __launch_bounds__(256) void wtrans(const float* __restrict__ wq,
                                              const float* __restrict__ wk,
                                              const float* __restrict__ wv,
                                              const float* __restrict__ wo,
                                              unsigned short* __restrict__ wT)
{
    __shared__ float tile[64][65];
    const int z = blockIdx.z;
    const float* w = (z == 0) ? wq : (z == 1) ? wk : (z == 2) ? wv : wo;
    unsigned short* dst = wT + (size_t)z * 1048576;
    const int t  = threadIdx.x;
    const int n0 = blockIdx.x * 64;
    const int k0 = blockIdx.y * 64;
    const int r  = t >> 2;
    const int c4 = (t & 3) * 16;
    #pragma unroll
    for (int j = 0; j < 4; ++j) {
        float4 v = *(const float4*)&w[(size_t)(k0 + r) * 1024 + n0 + c4 + j * 4];
        tile[r][c4 + j * 4 + 0] = v.x; tile[r][c4 + j * 4 + 1] = v.y;
        tile[r][c4 + j * 4 + 2] = v.z; tile[r][c4 + j * 4 + 3] = v.w;
    }
    __syncthreads();
    const int nn = t >> 2;
    const int kc = (t & 3) * 16;
    ushort8 o0, o1;
    #pragma unroll
    for (int j = 0; j < 8; ++j) o0[j] = f2bf(tile[kc + j][nn]);
    #pragma unroll
    for (int j = 0; j < 8; ++j) o1[j] = f2bf(tile[kc + 8 + j][nn]);
    *(ushort8*)&dst[(size_t)(n0 + nn) * 1024 + k0 + kc]     = o0;
    *(ushort8*)&dst[(size_t)(n0 + nn) * 1024 + k0 + kc + 8] = o1;
}

// ---------------------------------------------------------------------------
// Phase A: fused QKV.  BM=256, BN=64 per matrix, BK=64, 8 waves (4m x 2n).
// One barrier per K-tile; both k-slices' reads issued before the 48-MFMA
// cluster.  A 3-buf staged 2 ahead, B 2-buf staged 1 ahead, vmcnt(4).
// ---------------------------------------------------------------------------
__global__ __launch_bounds__(512) void qkv_mfma(
    const unsigned short* __restrict__ xb,       // half: [16384,1024] bf16
    const unsigned short* __restrict__ wqT,
    const unsigned short* __restrict__ wkT,
    const unsigned short* __restrict__ wvT,
    const float* __restrict__ bq, const float* __restrict__ bk,
    const float* __restrict__ bv,
    unsigned short* __restrict__ Qout,           // full [32768,1024]
    float* __restrict__ KV, float* __restrict__ Ks,
    int moff)
{
    __shared__ unsigned short Alds[3][256 * 64];     // 96 KB
    __shared__ unsigned short Blds[2][3][64 * 64];   // 48 KB  [buf][mat]
    __shared__ float redkv[16][64];
    __shared__ float redks[16][64];

    const int t = threadIdx.x;
    // bijective XCD swizzle: 1024 blocks, 8 XCDs, chunk 128.
    const unsigned int nlin = blockIdx.x + 16u * blockIdx.y;
    const unsigned int swz  = (nlin & 7u) * 128u + (nlin >> 3);
    const int h0   = (int)(swz & 15u) * 64;
    const int m0   = (int)(swz >> 4) * 256;
    const int mg   = moff + m0;
    const int bidx = mg >> 13;

    const int lane = t & 63, wid = t >> 6;
    const int wm = wid >> 1, wn = wid & 1;
    const int lr = lane & 15, quad = lane >> 4;

    const int sA   = wid * 64 + lane;
    const int xks0 = ((quad)     ^ (lr & 7)) * 8;
    const int xks1 = ((quad | 4) ^ (lr & 7)) * 8;
    const int arow = (wm * 64 + lr) * 64;
    const int brow = (wn * 32 + lr) * 64;

    // A unit u = 64 rows (512 chunks); all 8 waves issue 1 glds each.
    auto stA = [&](int kt, int u, int buf) {
        const int s = u * 512 + sA;
        const int r = s >> 3;
        const int j = (s & 7) ^ (r & 7);
        glds16(&xb[(size_t)(m0 + r) * 1024 + kt * 64 + j * 8],
               &Alds[buf][(u * 512 + wid * 64) * 8]);
    };
    // B matrix tile = 64 rows = 1 unit.
    auto stB = [&](const unsigned short* w, int mat, int kt, int buf) {
        const int r = sA >> 3;
        const int j = (sA & 7) ^ (r & 7);
        glds16(&w[(size_t)(h0 + r) * 1024 + kt * 64 + j * 8],
               &Blds[buf][mat][wid * 512]);
    };

    f32x4 accq[4][2], acck[4][2], accv[4][2];
    #pragma unroll
    for (int mi = 0; mi < 4; ++mi)
        #pragma unroll
        for (int nj = 0; nj < 2; ++nj) {
            accq[mi][nj] = (f32x4){0.f, 0.f, 0.f, 0.f};
            acck[mi][nj] = (f32x4){0.f, 0.f, 0.f, 0.f};
            accv[mi][nj] = (f32x4){0.f, 0.f, 0.f, 0.f};
        }

    // prologue: A(0)->abuf0, B(0)->bbuf0, A(1)->abuf1; drain A(0)+B(0)
    #pragma unroll
    for (int u = 0; u < 4; ++u) stA(0, u, 0);
    stB(wqT, 0, 0, 0); stB(wkT, 1, 0, 0); stB(wvT, 2, 0, 0);
    #pragma unroll
    for (int u = 0; u < 4; ++u) stA(1, u, 1);
    VM4();                                   // keep A(1), drain A(0)+B(0)
    KBAR();

    #pragma unroll
    for (int kt = 0; kt < 16; ++kt) {
        const int ab = kt % 3;
        const int bb = kt & 1;
        // ---- ks0 fragment reads (compiler will lgkm-count these) ----
        bf16x8 af0[4], af1[4], b0[3][2], b1[3][2];
        #pragma unroll
        for (int mi = 0; mi < 4; ++mi)
            af0[mi] = LDF(Alds[ab], arow + mi * 1024 + xks0);
        #pragma unroll
        for (int mt = 0; mt < 3; ++mt)
            #pragma unroll
            for (int nj = 0; nj < 2; ++nj)
                b0[mt][nj] = LDF(Blds[bb][mt], brow + nj * 1024 + xks0);
        // ---- staging: B(kt+1) first (older in FIFO), then A(kt+2) ----
        if (kt + 1 < 16) {
            stB(wqT, 0, kt + 1, (kt + 1) & 1);
            stB(wkT, 1, kt + 1, (kt + 1) & 1);
            stB(wvT, 2, kt + 1, (kt + 1) & 1);
        }
        if (kt + 2 < 16) {
            stA(kt + 2, 0, (kt + 2) % 3); stA(kt + 2, 1, (kt + 2) % 3);
            stA(kt + 2, 2, (kt + 2) % 3); stA(kt + 2, 3, (kt + 2) % 3);
        }
        // ---- ks1 fragment reads: drain on LDS pipe during ks0 MFMAs ----
        #pragma unroll
        for (int mi = 0; mi < 4; ++mi)
            af1[mi] = LDF(Alds[ab], arow + mi * 1024 + xks1);
        #pragma unroll
        for (int mt = 0; mt < 3; ++mt)
            #pragma unroll
            for (int nj = 0; nj < 2; ++nj)
                b1[mt][nj] = LDF(Blds[bb][mt], brow + nj * 1024 + xks1);

        __builtin_amdgcn_s_setprio(1);
        #pragma unroll
        for (int mi = 0; mi < 4; ++mi)
            #pragma unroll
            for (int nj = 0; nj < 2; ++nj) {
                accq[mi][nj] = __builtin_amdgcn_mfma_f32_16x16x32_bf16(af0[mi], b0[0][nj], accq[mi][nj], 0, 0, 0);
                acck[mi][nj] = __builtin_amdgcn_mfma_f32_16x16x32_bf16(af0[mi], b0[1][nj], acck[mi][nj], 0, 0, 0);
                accv[mi][nj] = __builtin_amdgcn_mfma_f32_16x16x32_bf16(af0[mi], b0[2][nj], accv[mi][nj], 0, 0, 0);
            }
        #pragma unroll
        for (int mi = 0; mi < 4; ++mi)
            #pragma unroll
            for (int nj = 0; nj < 2; ++nj) {
                accq[mi][nj] = __builtin_amdgcn_mfma_f32_16x16x32_bf16(af1[mi], b1[0][nj], accq[mi][nj], 0, 0, 0);
                acck[mi][nj] = __builtin_amdgcn_mfma_f32_16x16x32_bf16(af1[mi], b1[1][nj], acck[mi][nj], 0, 0, 0);
                accv[mi][nj] = __builtin_amdgcn_mfma_f32_16x16x32_bf16(af1[mi], b1[2][nj], accv[mi][nj], 0, 0, 0);
            }
        __builtin_amdgcn_s_setprio(0);

        // ---- drain for next tile + single barrier ----
        if (kt <= 13)      VM4();   // drain A(kt+1)+B(kt+1), keep A(kt+2)
        else if (kt == 14) VM0();   // tail: everything for kt=15
        if (kt < 15) KBAR();
    }

    // ---- epilogue: bias, elu+1, Q store (bf16), KV/Ksum partials ----
    float bqv[2], bkv[2], bvv[2];
    #pragma unroll
    for (int nj = 0; nj < 2; ++nj) {
        const int h = h0 + wn * 32 + nj * 16 + lr;
        bqv[nj] = bq[h]; bkv[nj] = bk[h]; bvv[nj] = bv[h];
    }
    float kvp[2] = {0.f, 0.f}, ksp[2] = {0.f, 0.f};
    #pragma unroll
    for (int mi = 0; mi < 4; ++mi)
        #pragma unroll
        for (int nj = 0; nj < 2; ++nj) {
            const int h = h0 + wn * 32 + nj * 16 + lr;
            #pragma unroll
            for (int r = 0; r < 4; ++r) {
                const int m = mg + wm * 64 + mi * 16 + quad * 4 + r;
                float q = elu1(accq[mi][nj][r] + bqv[nj]);
                Qout[(size_t)m * 1024 + h] = f2bf(q);
                float kk = elu1(acck[mi][nj][r] + bkv[nj]);
                float vv = accv[mi][nj][r] + bvv[nj];
                kvp[nj] = fmaf(kk, vv, kvp[nj]);
                ksp[nj] += kk;
            }
        }
    #pragma unroll
    for (int nj = 0; nj < 2; ++nj) {
        redkv[wm * 4 + quad][wn * 32 + nj * 16 + lr] = kvp[nj];
        redks[wm * 4 + quad][wn * 32 + nj * 16 + lr] = ksp[nj];
    }
    __syncthreads();
    if (t < 64) {
        float s = 0.f;
        #pragma unroll
        for (int g = 0; g < 16; ++g) s += redkv[g][t];
        atomicAdd(&KV[bidx * 1024 + h0 + t], s);
    } else if (t < 128) {
        const int c = t - 64;
        float s = 0.f;
        #pragma unroll
        for (int g = 0; g < 16; ++g) s += redks[g][c];
        atomicAdd(&Ks[bidx * 1024 + h0 + c], s);
    }
}

// ---------------------------------------------------------------------------
// V' = Q*KV / (Q*Ksum + 1e-6), elementwise in-place on Q (bf16)
// ---------------------------------------------------------------------------
__global__ __launch_bounds__(256) void vprime(
    unsigned short* __restrict__ Q,
    const float* __restrict__ KV, const float* __restrict__ Ks)
{
    const size_t idx  = (size_t)blockIdx.x * 256 + threadIdx.x;
    const size_t base = idx * 8;
    const int h = (int)(base & 1023);
    const int n = (int)(base >> 23);
    ushort8 q8 = *(ushort8*)&Q[base];
    const float* kvp = &KV[n * 1024 + h];
    const float* ksp = &Ks[n * 1024 + h];
    ushort8 o;
    #pragma unroll
    for (int j = 0; j < 8; ++j) {
        float qf = bf2f(q8[j]);
        float vp = qf * kvp[j] * __builtin_amdgcn_rcpf(fmaf(qf, ksp[j], 1e-6f));
        o[j] = f2bf(vp);
    }
    *(ushort8*)&Q[base] = o;
}

// ---------------------------------------------------------------------------
// Phase B: out = gelu(V' @ wo + bo).  256x256 tile, BK=64, 8 waves (2m x 4n).
// Same single-barrier K-tile structure; A 3-buf + B 2-buf = 160KB LDS.
// ---------------------------------------------------------------------------
__global__ __launch_bounds__(512) void out_mfma(
    const unsigned short* __restrict__ Vp,
    const unsigned short* __restrict__ woT,
    const float* __restrict__ bo, float* __restrict__ out)
{
    __shared__ unsigned short Alds[3][256 * 64];   // 96 KB
    __shared__ unsigned short Blds[2][256 * 64];   // 64 KB  (160KB total)

    const int t  = threadIdx.x;
    // bijective XCD swizzle: 512 blocks, chunk 64.
    const unsigned int nlin = blockIdx.x + 4u * blockIdx.y;
    const unsigned int swz  = (nlin & 7u) * 64u + (nlin >> 3);
    const int h0 = (int)(swz & 3u) * 256;
    const int m0 = (int)(swz >> 2) * 256;

    const int lane = t & 63, wid = t >> 6;
    const int wm = wid >> 2, wn = wid & 3;
    const int lr = lane & 15, quad = lane >> 4;

    const int sA   = wid * 64 + lane;
    const int xks0 = ((quad)     ^ (lr & 7)) * 8;
    const int xks1 = ((quad | 4) ^ (lr & 7)) * 8;
    const int arow = (wm * 128 + lr) * 64;
    const int brow = (wn * 64 + lr) * 64;

    auto stA = [&](int kt, int u, int buf) {
        const int s = u * 512 + sA;
        const int r = s >> 3;
        const int j = (s & 7) ^ (r & 7);
        glds16(&Vp[(size_t)(m0 + r) * 1024 + kt * 64 + j * 8],
               &Alds[buf][(u * 512 + wid * 64) * 8]);
    };
    auto stB = [&](int kt, int u, int buf) {
        const int s = u * 512 + sA;
        const int r = s >> 3;
        const int j = (s & 7) ^ (r & 7);
        glds16(&woT[(size_t)(h0 + r) * 1024 + kt * 64 + j * 8],
               &Blds[buf][(u * 512 + wid * 64) * 8]);
    };

    f32x4 acc[8][4];
    #pragma unroll
    for (int mr = 0; mr < 8; ++mr)
        #pragma unroll
        for (int nc = 0; nc < 4; ++nc) acc[mr][nc] = (f32x4){0.f, 0.f, 0.f, 0.f};

    // prologue: A(0) 4u, B(0) 4u, A(1) 4u; drain A(0)+B(0), keep A(1)
    #pragma unroll
    for (int u = 0; u < 4; ++u) stA(0, u, 0);
    #pragma unroll
    for (int u = 0; u < 4; ++u) stB(0, u, 0);
    #pragma unroll
    for (int u = 0; u < 4; ++u) stA(1, u, 1);
    VM4();
    KBAR();

    #pragma unroll
    for (int kt = 0; kt < 16; ++kt) {
        const int ab = kt % 3;
        const int bb = kt & 1;
        bf16x8 af[2][8], bfr[2][4];
        // ---- ks0 reads ----
        #pragma unroll
        for (int mh = 0; mh < 2; ++mh)
            #pragma unroll
            for (int mi = 0; mi < 4; ++mi)
                af[0][mh * 4 + mi] = LDF(Alds[ab], arow + mh * 4096 + mi * 1024 + xks0);
        #pragma unroll
        for (int nh = 0; nh < 2; ++nh)
            #pragma unroll
            for (int nj = 0; nj < 2; ++nj)
                bfr[0][nh * 2 + nj] = LDF(Blds[bb], brow + nh * 2048 + nj * 1024 + xks0);
        // ---- staging: B(kt+1) first, then A(kt+2) ----
        if (kt + 1 < 16) {
            stB(kt + 1, 0, (kt + 1) & 1); stB(kt + 1, 1, (kt + 1) & 1);
            stB(kt + 1, 2, (kt + 1) & 1); stB(kt + 1, 3, (kt + 1) & 1);
        }
        if (kt + 2 < 16) {
            stA(kt + 2, 0, (kt + 2) % 3); stA(kt + 2, 1, (kt + 2) % 3);
            stA(kt + 2, 2, (kt + 2) % 3); stA(kt + 2, 3, (kt + 2) % 3);
        }
        // ---- ks1 reads (drain during ks0 MFMAs) ----
        #pragma unroll
        for (int mh = 0; mh < 2; ++mh)
            #pragma unroll
            for (int mi = 0; mi < 4; ++mi)
                af[1][mh * 4 + mi] = LDF(Alds[ab], arow + mh * 4096 + mi * 1024 + xks1);
        #pragma unroll
        for (int nh = 0; nh < 2; ++nh)
            #pragma unroll
            for (int nj = 0; nj < 2; ++nj)
                bfr[1][nh * 2 + nj] = LDF(Blds[bb], brow + nh * 2048 + nj * 1024 + xks1);

        __builtin_amdgcn_s_setprio(1);
        #pragma unroll
        for (int s = 0; s < 2; ++s)
            #pragma unroll
            for (int mr = 0; mr < 8; ++mr)
                #pragma unroll
                for (int nc = 0; nc < 4; ++nc)
                    acc[mr][nc] = __builtin_amdgcn_mfma_f32_16x16x32_bf16(
                        af[s][mr], bfr[s][nc], acc[mr][nc], 0, 0, 0);
        __builtin_amdgcn_s_setprio(0);

        if (kt <= 13)      VM4();
        else if (kt == 14) VM0();
        if (kt < 15) KBAR();
    }

    float bov[4];
    #pragma unroll
    for (int nc = 0; nc < 4; ++nc) bov[nc] = bo[h0 + wn * 64 + nc * 16 + lr];
    #pragma unroll
    for (int mr = 0; mr < 8; ++mr)
        #pragma unroll
        for (int nc = 0; nc < 4; ++nc) {
            const int h = h0 + wn * 64 + nc * 16 + lr;
            #pragma unroll
            for (int r = 0; r < 4; ++r) {
                const int m = m0 + wm * 128 + mr * 16 + quad * 4 + r;
                out[(size_t)m * 1024 + h] = gelu_tanh(acc[mr][nc][r] + bov[nc]);
            }
        }
}

extern "C" void kernel_launch(void* const* d_in, const int* in_sizes, int n_in,
                              void* d_out, int out_size, void* d_ws, size_t ws_size,
                              hipStream_t stream)
{
    const float* x  = (const float*)d_in[0];
    const float* wq = (const float*)d_in[1];
    const float* bq = (const float*)d_in[2];
    const float* wk = (const float*)d_in[3];
    const float* bk = (const float*)d_in[4];
    const float* wv = (const float*)d_in[5];
    const float* bv = (const float*)d_in[6];
    const float* wo = (const float*)d_in[7];
    const float* bo = (const float*)d_in[8];
    float* out = (float*)d_out;

    // ws layout (bytes):
    //   [0, 64M)        Q / V' bf16  (32768 x 1024)
    //   [64M, 96M)      xb bf16 half (16384 x 1024), reused for both halves
    //   [96M, 104M)     wqT, wkT, wvT, woT bf16 (2MB each, contiguous)
    //   [104M, ...)     KV fp32 [4,1024], Ks fp32 [4,1024]
    char* wsb = (char*)d_ws;
    unsigned short* Qws = (unsigned short*)wsb;
    unsigned short* xb  = (unsigned short*)(wsb + 67108864ULL);
    unsigned short* wqT = (unsigned short*)(wsb + 100663296ULL);
    unsigned short* wkT = wqT + 1048576;
    unsigned short* wvT = wkT + 1048576;
    unsigned short* woT = wvT + 1048576;
    float* KV = (float*)(wsb + 100663296ULL + 4ULL * 2097152);
    float* Ks = KV + 4 * 1024;

    hipMemsetAsync(KV, 0, 2 * 4 * 1024 * sizeof(float), stream);

    wtrans<<<dim3(16, 16, 4), 256, 0, stream>>>(wq, wk, wv, wo, wqT);

    for (int half = 0; half < 2; ++half) {
        xconv<<<8192, 256, 0, stream>>>(x + (size_t)half * 16384 * 1024, xb);
        qkv_mfma<<<dim3(16, 64), 512, 0, stream>>>(xb, wqT, wkT, wvT, bq, bk, bv,
                                                   Qws, KV, Ks, half * 16384);
    }
    vprime<<<16384, 256, 0, stream>>>(Qws, KV, Ks);
    out_mfma<<<dim3(4, 128), 512, 0, stream>>>(Qws, woT, bo, out);
}

// Round 5
// 498.862 us; speedup vs baseline: 1.1546x; 1.0363x over previous
//
#include <hip/hip_runtime.h>
#include <math.h>
#include <stdint.h>

// LinearAttention  N=4, S=8192, D_IN=1024, ATTN_DIM=1024, OUT_DIM=1024
// R9: cross-tile register pipeline.  Each k-slice's fragments are ds_read one
// half-tile BEFORE use, so reads drain under the other slice's MFMA cluster:
//   iter t: read ks1[t]; MFMA-ks0[t];
//           vmcnt(0)+lgkmcnt(0)+barrier;          (tile t+1 resident, tile-t
//           read ks0[t+1]; stage(t+2); MFMA-ks1[t] reads all drained -> 2-buf ok)
// Single barrier/tile; vmcnt(0) is exact (only t+1's loads outstanding, issued
// a full tile (~2000cy) earlier).  __launch_bounds__(512,2) lifts the VGPR cap
// to 256 (R8's VGPR=116 shows the compiler re-serialized reads to save regs;
// occupancy is LDS-capped at 1 block/CU so registers are free).
// Same structure for out_mfma (fixes its R8 spill regression).
// Numerics identical.

#define S_LEN 8192

typedef __attribute__((ext_vector_type(8))) __bf16 bf16x8;
typedef __attribute__((ext_vector_type(8))) unsigned short ushort8;
typedef __attribute__((ext_vector_type(4))) float f32x4;

__device__ __forceinline__ unsigned short f2bf(float f) {
    unsigned int u = __builtin_bit_cast(unsigned int, f);
    unsigned int r = (u + 0x7fffu + ((u >> 16) & 1u)) >> 16;   // RNE
    return (unsigned short)r;
}
__device__ __forceinline__ float bf2f(unsigned short s) {
    unsigned int u = ((unsigned int)s) << 16;
    return __builtin_bit_cast(float, u);
}
__device__ __forceinline__ float elu1(float v) { return v > 0.f ? v + 1.f : __expf(v); }
__device__ __forceinline__ float gelu_tanh(float v) {
    float u = 1.5957691216057308f * (v + 0.044715f * v * v * v);
    float e = __expf(u);
    float th = 1.f - 2.f / (e + 1.f);
    return 0.5f * v * (1.f + th);
}
__device__ __forceinline__ void glds16(const void* g, void* l) {
    __builtin_amdgcn_global_load_lds(
        (const __attribute__((address_space(1))) unsigned int*)(uintptr_t)g,
        (__attribute__((address_space(3))) unsigned int*)(uintptr_t)l, 16, 0, 0);
}

#define KBAR()  asm volatile("s_barrier" ::: "memory")
#define LGKM0() do { asm volatile("s_waitcnt lgkmcnt(0)" ::: "memory"); \
                     __builtin_amdgcn_sched_barrier(0); } while (0)
#define VM8()   asm volatile("s_waitcnt vmcnt(8)" ::: "memory")
#define VM7()   asm volatile("s_waitcnt vmcnt(7)" ::: "memory")
#define VM0()   asm volatile("s_waitcnt vmcnt(0)" ::: "memory")

#define LDF(P, OFF) __builtin_bit_cast(bf16x8, *(const ushort8*)&(P)[OFF])

// ---------------------------------------------------------------------------
// x fp32 -> bf16, one half (16384 rows) per call
// ---------------------------------------------------------------------------
__global__ __launch_bounds__(256) void xconv(const float* __restrict__ x,
                                             unsigned short* __restrict__ xb)
{
    const size_t base = ((size_t)blockIdx.x * 256 + threadIdx.x) * 8;
    float4 a = *(const float4*)&x[base];
    float4 b = *(const float4*)&x[base + 4];
    ushort8 o;
    o[0] = f2bf(a.x); o[1] = f2bf(a.y); o[2] = f2bf(a.z); o[3] = f2bf(a.w);
    o[4] = f2bf(b.x); o[5] = f2bf(b.y); o[6] = f2bf(b.z); o[7] = f2bf(b.w);
    *(ushort8*)&xb[base] = o;
}

// ---------------------------------------------------------------------------
// weight transpose + convert, all 4 matrices in one launch (blockIdx.z)
// ---------------------------------------------------------------------------
__global__ __launch_bounds__(256) void wtrans(const float* __restrict__ wq,
                                              const float* __restrict__ wk,
                                              const float* __restrict__ wv,
                                              const float* __restrict__ wo,
                                              unsigned short* __restrict__ wT)
{
    __shared__ float tile[64][65];
    const int z = blockIdx.z;
    const float* w = (z == 0) ? wq : (z == 1) ? wk : (z == 2) ? wv : wo;
    unsigned short* dst = wT + (size_t)z * 1048576;
    const int t  = threadIdx.x;
    const int n0 = blockIdx.x * 64;
    const int k0 = blockIdx.y * 64;
    const int r  = t >> 2;
    const int c4 = (t & 3) * 16;
    #pragma unroll
    for (int j = 0; j < 4; ++j) {
        float4 v = *(const float4*)&w[(size_t)(k0 + r) * 1024 + n0 + c4 + j * 4];
        tile[r][c4 + j * 4 + 0] = v.x; tile[r][c4 + j * 4 + 1] = v.y;
        tile[r][c4 + j * 4 + 2] = v.z; tile[r][c4 + j * 4 + 3] = v.w;
    }
    __syncthreads();
    const int nn = t >> 2;
    const int kc = (t & 3) * 16;
    ushort8 o0, o1;
    #pragma unroll
    for (int j = 0; j < 8; ++j) o0[j] = f2bf(tile[kc + j][nn]);
    #pragma unroll
    for (int j = 0; j < 8; ++j) o1[j] = f2bf(tile[kc + 8 + j][nn]);
    *(ushort8*)&dst[(size_t)(n0 + nn) * 1024 + k0 + kc]     = o0;
    *(ushort8*)&dst[(size_t)(n0 + nn) * 1024 + k0 + kc + 8] = o1;
}

// ---------------------------------------------------------------------------
// Phase A: fused QKV.  BM=256, BN=64 per matrix, BK=64, 8 waves (4m x 2n).
// Cross-tile register pipeline, single barrier/tile, A/B double-buffered.
// ---------------------------------------------------------------------------
__global__ __launch_bounds__(512, 2) void qkv_mfma(
    const unsigned short* __restrict__ xb,       // half: [16384,1024] bf16
    const unsigned short* __restrict__ wqT,
    const unsigned short* __restrict__ wkT,
    const unsigned short* __restrict__ wvT,
    const float* __restrict__ bq, const float* __restrict__ bk,
    const float* __restrict__ bv,
    unsigned short* __restrict__ Qout,           // full [32768,1024]
    float* __restrict__ KV, float* __restrict__ Ks,
    int moff)
{
    __shared__ unsigned short Alds[2][256 * 64];     // 64 KB
    __shared__ unsigned short Blds[2][3][64 * 64];   // 48 KB  [buf][mat]
    __shared__ float redkv[16][64];
    __shared__ float redks[16][64];

    const int t = threadIdx.x;
    // bijective XCD swizzle: 1024 blocks, 8 XCDs, chunk 128.
    const unsigned int nlin = blockIdx.x + 16u * blockIdx.y;
    const unsigned int swz  = (nlin & 7u) * 128u + (nlin >> 3);
    const int h0   = (int)(swz & 15u) * 64;
    const int m0   = (int)(swz >> 4) * 256;
    const int mg   = moff + m0;
    const int bidx = mg >> 13;

    const int lane = t & 63, wid = t >> 6;
    const int wm = wid >> 1, wn = wid & 1;
    const int lr = lane & 15, quad = lane >> 4;

    const int sA   = wid * 64 + lane;
    const int xks0 = ((quad)     ^ (lr & 7)) * 8;
    const int xks1 = ((quad | 4) ^ (lr & 7)) * 8;
    const int arow = (wm * 64 + lr) * 64;
    const int brow = (wn * 32 + lr) * 64;

    // A unit u = 64 rows (512 chunks); all 8 waves issue 1 glds each.
    auto stA = [&](int kt, int u, int buf) {
        const int s = u * 512 + sA;
        const int r = s >> 3;
        const int j = (s & 7) ^ (r & 7);
        glds16(&xb[(size_t)(m0 + r) * 1024 + kt * 64 + j * 8],
               &Alds[buf][(u * 512 + wid * 64) * 8]);
    };
    auto stB = [&](const unsigned short* w, int mat, int kt, int buf) {
        const int r = sA >> 3;
        const int j = (sA & 7) ^ (r & 7);
        glds16(&w[(size_t)(h0 + r) * 1024 + kt * 64 + j * 8],
               &Blds[buf][mat][wid * 512]);
    };

    f32x4 accq[4][2], acck[4][2], accv[4][2];
    #pragma unroll
    for (int mi = 0; mi < 4; ++mi)
        #pragma unroll
        for (int nj = 0; nj < 2; ++nj) {
            accq[mi][nj] = (f32x4){0.f, 0.f, 0.f, 0.f};
            acck[mi][nj] = (f32x4){0.f, 0.f, 0.f, 0.f};
            accv[mi][nj] = (f32x4){0.f, 0.f, 0.f, 0.f};
        }

    // prologue: stage tiles 0 and 1; drain tile 0; read ks0[0]
    #pragma unroll
    for (int u = 0; u < 4; ++u) stA(0, u, 0);
    stB(wqT, 0, 0, 0); stB(wkT, 1, 0, 0); stB(wvT, 2, 0, 0);
    #pragma unroll
    for (int u = 0; u < 4; ++u) stA(1, u, 1);
    stB(wqT, 0, 1, 1); stB(wkT, 1, 1, 1); stB(wvT, 2, 1, 1);
    VM7();                                   // drain tile0 (keep tile1's 7)
    KBAR();

    bf16x8 af0[4], af1[4], b0[3][2], b1[3][2];
    #pragma unroll
    for (int mi = 0; mi < 4; ++mi)
        af0[mi] = LDF(Alds[0], arow + mi * 1024 + xks0);
    #pragma unroll
    for (int mt = 0; mt < 3; ++mt)
        #pragma unroll
        for (int nj = 0; nj < 2; ++nj)
            b0[mt][nj] = LDF(Blds[0][mt], brow + nj * 1024 + xks0);

    #pragma unroll
    for (int kt = 0; kt < 16; ++kt) {
        const int ab = kt & 1, nb = (kt + 1) & 1;
        // ---- read ks1[kt] -> set1 (drains under MFMA-ks0) ----
        #pragma unroll
        for (int mi = 0; mi < 4; ++mi)
            af1[mi] = LDF(Alds[ab], arow + mi * 1024 + xks1);
        #pragma unroll
        for (int mt = 0; mt < 3; ++mt)
            #pragma unroll
            for (int nj = 0; nj < 2; ++nj)
                b1[mt][nj] = LDF(Blds[ab][mt], brow + nj * 1024 + xks1);
        // ---- MFMA ks0 (fragments read last iter) ----
        __builtin_amdgcn_s_setprio(1);
        #pragma unroll
        for (int mi = 0; mi < 4; ++mi)
            #pragma unroll
            for (int nj = 0; nj < 2; ++nj) {
                accq[mi][nj] = __builtin_amdgcn_mfma_f32_16x16x32_bf16(af0[mi], b0[0][nj], accq[mi][nj], 0, 0, 0);
                acck[mi][nj] = __builtin_amdgcn_mfma_f32_16x16x32_bf16(af0[mi], b0[1][nj], acck[mi][nj], 0, 0, 0);
                accv[mi][nj] = __builtin_amdgcn_mfma_f32_16x16x32_bf16(af0[mi], b0[2][nj], accv[mi][nj], 0, 0, 0);
            }
        __builtin_amdgcn_s_setprio(0);

        if (kt < 15) {
            VM0();        // drain tile kt+1 staging (issued a full tile ago)
            LGKM0();      // tile-kt reads all complete before others overwrite
            KBAR();
            // ---- read ks0[kt+1] -> set0 (drains under MFMA-ks1) ----
            #pragma unroll
            for (int mi = 0; mi < 4; ++mi)
                af0[mi] = LDF(Alds[nb], arow + mi * 1024 + xks0);
            #pragma unroll
            for (int mt = 0; mt < 3; ++mt)
                #pragma unroll
                for (int nj = 0; nj < 2; ++nj)
                    b0[mt][nj] = LDF(Blds[nb][mt], brow + nj * 1024 + xks0);
            // ---- stage tile kt+2 into buf ab (fully read, race-free) ----
            if (kt + 2 < 16) {
                stB(wqT, 0, kt + 2, ab);
                stB(wkT, 1, kt + 2, ab);
                stB(wvT, 2, kt + 2, ab);
                stA(kt + 2, 0, ab); stA(kt + 2, 1, ab);
                stA(kt + 2, 2, ab); stA(kt + 2, 3, ab);
            }
        }
        // ---- MFMA ks1 ----
        __builtin_amdgcn_s_setprio(1);
        #pragma unroll
        for (int mi = 0; mi < 4; ++mi)
            #pragma unroll
            for (int nj = 0; nj < 2; ++nj) {
                accq[mi][nj] = __builtin_amdgcn_mfma_f32_16x16x32_bf16(af1[mi], b1[0][nj], accq[mi][nj], 0, 0, 0);
                acck[mi][nj] = __builtin_amdgcn_mfma_f32_16x16x32_bf16(af1[mi], b1[1][nj], acck[mi][nj], 0, 0, 0);
                accv[mi][nj] = __builtin_amdgcn_mfma_f32_16x16x32_bf16(af1[mi], b1[2][nj], accv[mi][nj], 0, 0, 0);
            }
        __builtin_amdgcn_s_setprio(0);
    }

    // ---- epilogue: bias, elu+1, Q store (bf16), KV/Ksum partials ----
    float bqv[2], bkv[2], bvv[2];
    #pragma unroll
    for (int nj = 0; nj < 2; ++nj) {
        const int h = h0 + wn * 32 + nj * 16 + lr;
        bqv[nj] = bq[h]; bkv[nj] = bk[h]; bvv[nj] = bv[h];
    }
    float kvp[2] = {0.f, 0.f}, ksp[2] = {0.f, 0.f};
    #pragma unroll
    for (int mi = 0; mi < 4; ++mi)
        #pragma unroll
        for (int nj = 0; nj < 2; ++nj) {
            const int h = h0 + wn * 32 + nj * 16 + lr;
            #pragma unroll
            for (int r = 0; r < 4; ++r) {
                const int m = mg + wm * 64 + mi * 16 + quad * 4 + r;
                float q = elu1(accq[mi][nj][r] + bqv[nj]);
                Qout[(size_t)m * 1024 + h] = f2bf(q);
                float kk = elu1(acck[mi][nj][r] + bkv[nj]);
                float vv = accv[mi][nj][r] + bvv[nj];
                kvp[nj] = fmaf(kk, vv, kvp[nj]);
                ksp[nj] += kk;
            }
        }
    #pragma unroll
    for (int nj = 0; nj < 2; ++nj) {
        redkv[wm * 4 + quad][wn * 32 + nj * 16 + lr] = kvp[nj];
        redks[wm * 4 + quad][wn * 32 + nj * 16 + lr] = ksp[nj];
    }
    __syncthreads();
    if (t < 64) {
        float s = 0.f;
        #pragma unroll
        for (int g = 0; g < 16; ++g) s += redkv[g][t];
        atomicAdd(&KV[bidx * 1024 + h0 + t], s);
    } else if (t < 128) {
        const int c = t - 64;
        float s = 0.f;
        #pragma unroll
        for (int g = 0; g < 16; ++g) s += redks[g][c];
        atomicAdd(&Ks[bidx * 1024 + h0 + c], s);
    }
}

// ---------------------------------------------------------------------------
// V' = Q*KV / (Q*Ksum + 1e-6), elementwise in-place on Q (bf16)
// ---------------------------------------------------------------------------
__global__ __launch_bounds__(256) void vprime(
    unsigned short* __restrict__ Q,
    const float* __restrict__ KV, const float* __restrict__ Ks)
{
    const size_t idx  = (size_t)blockIdx.x * 256 + threadIdx.x;
    const size_t base = idx * 8;
    const int h = (int)(base & 1023);
    const int n = (int)(base >> 23);
    ushort8 q8 = *(ushort8*)&Q[base];
    const float* kvp = &KV[n * 1024 + h];
    const float* ksp = &Ks[n * 1024 + h];
    ushort8 o;
    #pragma unroll
    for (int j = 0; j < 8; ++j) {
        float qf = bf2f(q8[j]);
        float vp = qf * kvp[j] * __builtin_amdgcn_rcpf(fmaf(qf, ksp[j], 1e-6f));
        o[j] = f2bf(vp);
    }
    *(ushort8*)&Q[base] = o;
}

// ---------------------------------------------------------------------------
// Phase B: out = gelu(V' @ wo + bo).  256x256 tile, BK=64, 8 waves (2m x 4n).
// Same cross-tile register pipeline; A/B double-buffered (128KB LDS).
// ---------------------------------------------------------------------------
__global__ __launch_bounds__(512, 2) void out_mfma(
    const unsigned short* __restrict__ Vp,
    const unsigned short* __restrict__ woT,
    const float* __restrict__ bo, float* __restrict__ out)
{
    __shared__ unsigned short Alds[2][256 * 64];   // 64 KB
    __shared__ unsigned short Blds[2][256 * 64];   // 64 KB

    const int t  = threadIdx.x;
    // bijective XCD swizzle: 512 blocks, chunk 64.
    const unsigned int nlin = blockIdx.x + 4u * blockIdx.y;
    const unsigned int swz  = (nlin & 7u) * 64u + (nlin >> 3);
    const int h0 = (int)(swz & 3u) * 256;
    const int m0 = (int)(swz >> 2) * 256;

    const int lane = t & 63, wid = t >> 6;
    const int wm = wid >> 2, wn = wid & 3;
    const int lr = lane & 15, quad = lane >> 4;

    const int sA   = wid * 64 + lane;
    const int xks0 = ((quad)     ^ (lr & 7)) * 8;
    const int xks1 = ((quad | 4) ^ (lr & 7)) * 8;
    const int arow = (wm * 128 + lr) * 64;
    const int brow = (wn * 64 + lr) * 64;

    auto stA = [&](int kt, int u, int buf) {
        const int s = u * 512 + sA;
        const int r = s >> 3;
        const int j = (s & 7) ^ (r & 7);
        glds16(&Vp[(size_t)(m0 + r) * 1024 + kt * 64 + j * 8],
               &Alds[buf][(u * 512 + wid * 64) * 8]);
    };
    auto stB = [&](int kt, int u, int buf) {
        const int s = u * 512 + sA;
        const int r = s >> 3;
        const int j = (s & 7) ^ (r & 7);
        glds16(&woT[(size_t)(h0 + r) * 1024 + kt * 64 + j * 8],
               &Blds[buf][(u * 512 + wid * 64) * 8]);
    };

    f32x4 acc[8][4];
    #pragma unroll
    for (int mr = 0; mr < 8; ++mr)
        #pragma unroll
        for (int nc = 0; nc < 4; ++nc) acc[mr][nc] = (f32x4){0.f, 0.f, 0.f, 0.f};

    // prologue: stage tiles 0 and 1 (8 glds each); drain tile 0; read ks0[0]
    #pragma unroll
    for (int u = 0; u < 4; ++u) stA(0, u, 0);
    #pragma unroll
    for (int u = 0; u < 4; ++u) stB(0, u, 0);
    #pragma unroll
    for (int u = 0; u < 4; ++u) stA(1, u, 1);
    #pragma unroll
    for (int u = 0; u < 4; ++u) stB(1, u, 1);
    VM8();                                   // drain tile0 (keep tile1's 8)
    KBAR();

    bf16x8 af0[8], af1[8], b0[4], b1[4];
    #pragma unroll
    for (int mh = 0; mh < 2; ++mh)
        #pragma unroll
        for (int mi = 0; mi < 4; ++mi)
            af0[mh * 4 + mi] = LDF(Alds[0], arow + mh * 4096 + mi * 1024 + xks0);
    #pragma unroll
    for (int nh = 0; nh < 2; ++nh)
        #pragma unroll
        for (int nj = 0; nj < 2; ++nj)
            b0[nh * 2 + nj] = LDF(Blds[0], brow + nh * 2048 + nj * 1024 + xks0);

    #pragma unroll
    for (int kt = 0; kt < 16; ++kt) {
        const int ab = kt & 1, nb = (kt + 1) & 1;
        // ---- read ks1[kt] -> set1 ----
        #pragma unroll
        for (int mh = 0; mh < 2; ++mh)
            #pragma unroll
            for (int mi = 0; mi < 4; ++mi)
                af1[mh * 4 + mi] = LDF(Alds[ab], arow + mh * 4096 + mi * 1024 + xks1);
        #pragma unroll
        for (int nh = 0; nh < 2; ++nh)
            #pragma unroll
            for (int nj = 0; nj < 2; ++nj)
                b1[nh * 2 + nj] = LDF(Blds[ab], brow + nh * 2048 + nj * 1024 + xks1);
        // ---- MFMA ks0 ----
        __builtin_amdgcn_s_setprio(1);
        #pragma unroll
        for (int mr = 0; mr < 8; ++mr)
            #pragma unroll
            for (int nc = 0; nc < 4; ++nc)
                acc[mr][nc] = __builtin_amdgcn_mfma_f32_16x16x32_bf16(
                    af0[mr], b0[nc], acc[mr][nc], 0, 0, 0);
        __builtin_amdgcn_s_setprio(0);

        if (kt < 15) {
            VM0();
            LGKM0();
            KBAR();
            // ---- read ks0[kt+1] -> set0 ----
            #pragma unroll
            for (int mh = 0; mh < 2; ++mh)
                #pragma unroll
                for (int mi = 0; mi < 4; ++mi)
                    af0[mh * 4 + mi] = LDF(Alds[nb], arow + mh * 4096 + mi * 1024 + xks0);
            #pragma unroll
            for (int nh = 0; nh < 2; ++nh)
                #pragma unroll
                for (int nj = 0; nj < 2; ++nj)
                    b0[nh * 2 + nj] = LDF(Blds[nb], brow + nh * 2048 + nj * 1024 + xks0);
            // ---- stage tile kt+2 into buf ab ----
            if (kt + 2 < 16) {
                stB(kt + 2, 0, ab); stB(kt + 2, 1, ab);
                stB(kt + 2, 2, ab); stB(kt + 2, 3, ab);
                stA(kt + 2, 0, ab); stA(kt + 2, 1, ab);
                stA(kt + 2, 2, ab); stA(kt + 2, 3, ab);
            }
        }
        // ---- MFMA ks1 ----
        __builtin_amdgcn_s_setprio(1);
        #pragma unroll
        for (int mr = 0; mr < 8; ++mr)
            #pragma unroll
            for (int nc = 0; nc < 4; ++nc)
                acc[mr][nc] = __builtin_amdgcn_mfma_f32_16x16x32_bf16(
                    af1[mr], b1[nc], acc[mr][nc], 0, 0, 0);
        __builtin_amdgcn_s_setprio(0);
    }

    float bov[4];
    #pragma unroll
    for (int nc = 0; nc < 4; ++nc) bov[nc] = bo[h0 + wn * 64 + nc * 16 + lr];
    #pragma unroll
    for (int mr = 0; mr < 8; ++mr)
        #pragma unroll
        for (int nc = 0; nc < 4; ++nc) {
            const int h = h0 + wn * 64 + nc * 16 + lr;
            #pragma unroll
            for (int r = 0; r < 4; ++r) {
                const int m = m0 + wm * 128 + mr * 16 + quad * 4 + r;
                out[(size_t)m * 1024 + h] = gelu_tanh(acc[mr][nc][r] + bov[nc]);
            }
        }
}

extern "C" void kernel_launch(void* const* d_in, const int* in_sizes, int n_in,
                              void* d_out, int out_size, void* d_ws, size_t ws_size,
                              hipStream_t stream)
{
    const float* x  = (const float*)d_in[0];
    const float* wq = (const float*)d_in[1];
    const float* bq = (const float*)d_in[2];
    const float* wk = (const float*)d_in[3];
    const float* bk = (const float*)d_in[4];
    const float* wv = (const float*)d_in[5];
    const float* bv = (const float*)d_in[6];
    const float* wo = (const float*)d_in[7];
    const float* bo = (const float*)d_in[8];
    float* out = (float*)d_out;

    // ws layout (bytes):
    //   [0, 64M)        Q / V' bf16  (32768 x 1024)
    //   [64M, 96M)      xb bf16 half (16384 x 1024), reused for both halves
    //   [96M, 104M)     wqT, wkT, wvT, woT bf16 (2MB each, contiguous)
    //   [104M, ...)     KV fp32 [4,1024], Ks fp32 [4,1024]
    char* wsb = (char*)d_ws;
    unsigned short* Qws = (unsigned short*)wsb;
    unsigned short* xb  = (unsigned short*)(wsb + 67108864ULL);
    unsigned short* wqT = (unsigned short*)(wsb + 100663296ULL);
    unsigned short* wkT = wqT + 1048576;
    unsigned short* wvT = wkT + 1048576;
    unsigned short* woT = wvT + 1048576;
    float* KV = (float*)(wsb + 100663296ULL + 4ULL * 2097152);
    float* Ks = KV + 4 * 1024;

    hipMemsetAsync(KV, 0, 2 * 4 * 1024 * sizeof(float), stream);

    wtrans<<<dim3(16, 16, 4), 256, 0, stream>>>(wq, wk, wv, wo, wqT);

    for (int half = 0; half < 2; ++half) {
        xconv<<<8192, 256, 0, stream>>>(x + (size_t)half * 16384 * 1024, xb);
        qkv_mfma<<<dim3(16, 64), 512, 0, stream>>>(xb, wqT, wkT, wvT, bq, bk, bv,
                                                   Qws, KV, Ks, half * 16384);
    }
    vprime<<<16384, 256, 0, stream>>>(Qws, KV, Ks);
    out_mfma<<<dim3(4, 128), 512, 0, stream>>>(Qws, woT, bo, out);
}